// Round 9
// baseline (388.283 us; speedup 1.0000x reference)
//
#include <hip/hip_runtime.h>
#include <math.h>

namespace {

constexpr int kT = 1024;
constexpr int kH = 1024;
constexpr int kNQ = 16;
constexpr int kNKV = 4;
constexpr int kD = 64;
constexpr int kQKV = (kNQ + 2 * kNKV) * kD;   // 1536
constexpr int kIDense = 4096;
constexpr int kIMoe = 512;
constexpr int kE = 8;
constexpr float kEps = 1e-6f;

typedef __attribute__((ext_vector_type(8))) short short8;
typedef __attribute__((ext_vector_type(4))) float f32x4;

__device__ __forceinline__ ushort f2bf(float f) {
    union { float f; uint32_t u; } v; v.f = f;
    uint32_t r = (v.u + 0x7fffu + ((v.u >> 16) & 1u)) >> 16;
    return (ushort)r;
}
__device__ __forceinline__ void gload16(const void* g, void* l) {
    __builtin_amdgcn_global_load_lds(
        (const __attribute__((address_space(1))) void*)g,
        (__attribute__((address_space(3))) void*)l, 16, 0, 0);
}

// ---------------------------------------------------------------------------
// add + RMSNorm: r_out = x + res; h = rmsnorm(r_out)*w  -> h32 (f32) + h16 (bf16)
// ---------------------------------------------------------------------------
__global__ __launch_bounds__(256) void add_rmsnorm_kernel(
    const float* __restrict__ x, const float* __restrict__ res,
    const float* __restrict__ w, float* __restrict__ h32,
    ushort* __restrict__ h16, float* __restrict__ r_out)
{
    __shared__ float red[4];
    const int t = blockIdx.x;
    const int i = threadIdx.x;
    const size_t base = (size_t)t * kH;
    float4 a = reinterpret_cast<const float4*>(x + base)[i];
    float4 b = reinterpret_cast<const float4*>(res + base)[i];
    float4 s = make_float4(a.x + b.x, a.y + b.y, a.z + b.z, a.w + b.w);
    reinterpret_cast<float4*>(r_out + base)[i] = s;
    float ss = s.x * s.x + s.y * s.y + s.z * s.z + s.w * s.w;
    #pragma unroll
    for (int off = 32; off > 0; off >>= 1) ss += __shfl_down(ss, off);
    if ((i & 63) == 0) red[i >> 6] = ss;
    __syncthreads();
    const float tot = red[0] + red[1] + red[2] + red[3];
    const float inv = rsqrtf(tot * (1.0f / kH) + kEps);
    float4 wv = reinterpret_cast<const float4*>(w)[i];
    float4 o = make_float4(s.x * inv * wv.x, s.y * inv * wv.y,
                           s.z * inv * wv.z, s.w * inv * wv.w);
    reinterpret_cast<float4*>(h32 + base)[i] = o;
    ushort4 u;
    u.x = f2bf(o.x); u.y = f2bf(o.y); u.z = f2bf(o.z); u.w = f2bf(o.w);
    reinterpret_cast<ushort4*>(h16 + base)[i] = u;
}

// ---------------------------------------------------------------------------
// Fast transpose + f32 -> bf16: W (R x Cn f32, row stride ld_w) -> WT (Cn x R).
// ---------------------------------------------------------------------------
__global__ __launch_bounds__(256) void transpose_bf16_kernel(
    const float* __restrict__ W, ushort* __restrict__ WT,
    int R, int Cn, int ld_w, long w_z_stride, long wt_z_stride)
{
    __shared__ float tile[64 * 65];
    const int z = blockIdx.z;
    const float* Wz = W + (size_t)z * w_z_stride;
    ushort* WTz = WT + (size_t)z * wt_z_stride;
    const int r0 = blockIdx.y * 64;
    const int c0 = blockIdx.x * 64;
    const int tid = threadIdx.x;
    const int lr = tid >> 4;
    const int lc = (tid & 15) * 4;
    #pragma unroll
    for (int p = 0; p < 4; p++) {
        const int row = p * 16 + lr;
        float4 v = *reinterpret_cast<const float4*>(
            &Wz[(size_t)(r0 + row) * ld_w + c0 + lc]);
        tile[row * 65 + lc + 0] = v.x;
        tile[row * 65 + lc + 1] = v.y;
        tile[row * 65 + lc + 2] = v.z;
        tile[row * 65 + lc + 3] = v.w;
    }
    __syncthreads();
    const int ocl = tid >> 2;
    const int q = tid & 3;
    ushort u[16];
    #pragma unroll
    for (int e = 0; e < 16; e++)
        u[e] = f2bf(tile[(q * 16 + e) * 65 + ocl]);
    ushort* dst = &WTz[(size_t)(c0 + ocl) * R + r0 + q * 16];
    *reinterpret_cast<short8*>(dst) = *reinterpret_cast<short8*>(&u[0]);
    *reinterpret_cast<short8*>(dst + 8) = *reinterpret_cast<short8*>(&u[8]);
}

// ---------------------------------------------------------------------------
// bf16 MFMA GEMM, 64x64 tile, BK=64, 256 thr (4 waves, 2x2 frags).
// Both operands bf16 via global_load_lds, source-chunk skewed (r8 structure).
// ---------------------------------------------------------------------------
template <bool GATED>
__global__ __launch_bounds__(256) void mgemm_kernel(
    const ushort* __restrict__ A, const ushort* __restrict__ B,
    float* __restrict__ Cf, ushort* __restrict__ C16,
    const float* __restrict__ scale,
    int lda, int ldb, int ldc, int kc,
    int gate_off_rows, long b_z_stride, int c_z_col, int k_z_off,
    int scale_stride, int atomic_flag)
{
    __shared__ __align__(16) ushort As[64 * 64];
    __shared__ __align__(16) ushort Bs[64 * 64];
    __shared__ __align__(16) ushort Us[GATED ? 64 * 64 : 8];

    const int z = blockIdx.z;
    const int m0 = blockIdx.y * 64;
    const int n0 = blockIdx.x * 64;
    const int tid = threadIdx.x;
    const ushort* Bz = B + (size_t)z * b_z_stride;
    const int k0 = z * k_z_off;

    const int arow = tid >> 3;
    const int achk = tid & 7;

    const int lane = tid & 63;
    const int wave = tid >> 6;
    const int wr = (wave >> 1) * 32;
    const int wc = (wave & 1) * 32;
    const int lrow = lane & 15;
    const int lg = lane >> 4;

    f32x4 accg[2][2] = {};
    f32x4 accu[2][2] = {};

    for (int kk0 = 0; kk0 < kc; kk0 += 64) {
        const int kbase = k0 + kk0;
        #pragma unroll
        for (int c = 0; c < 2; c++) {
            const int row = c * 32 + arow;
            const int cs = (achk + (row & 7)) & 7;
            gload16(A + (size_t)(m0 + row) * lda + kbase + cs * 8,
                    (char*)As + c * 4096 + tid * 16);
            gload16(Bz + (size_t)(n0 + row) * ldb + kbase + cs * 8,
                    (char*)Bs + c * 4096 + tid * 16);
            if constexpr (GATED)
                gload16(Bz + (size_t)(gate_off_rows + n0 + row) * ldb + kbase + cs * 8,
                        (char*)Us + c * 4096 + tid * 16);
        }
        __syncthreads();

        short8 af[2][2], bfr[2][2];
        #pragma unroll
        for (int mf = 0; mf < 2; mf++)
            #pragma unroll
            for (int kk = 0; kk < 2; kk++) {
                const int r = wr + mf * 16 + lrow;
                const int sl = ((kk * 4 + lg) - (r & 7)) & 7;
                af[mf][kk] = *reinterpret_cast<const short8*>(
                    (const char*)As + r * 128 + sl * 16);
            }
        #pragma unroll
        for (int nf = 0; nf < 2; nf++)
            #pragma unroll
            for (int kk = 0; kk < 2; kk++) {
                const int n = wc + nf * 16 + lrow;
                const int sl = ((kk * 4 + lg) - (n & 7)) & 7;
                bfr[nf][kk] = *reinterpret_cast<const short8*>(
                    (const char*)Bs + n * 128 + sl * 16);
            }
        #pragma unroll
        for (int mf = 0; mf < 2; mf++)
            #pragma unroll
            for (int nf = 0; nf < 2; nf++)
                #pragma unroll
                for (int kk = 0; kk < 2; kk++)
                    accg[mf][nf] = __builtin_amdgcn_mfma_f32_16x16x32_bf16(
                        af[mf][kk], bfr[nf][kk], accg[mf][nf], 0, 0, 0);
        if constexpr (GATED) {
            short8 uf[2][2];
            #pragma unroll
            for (int nf = 0; nf < 2; nf++)
                #pragma unroll
                for (int kk = 0; kk < 2; kk++) {
                    const int n = wc + nf * 16 + lrow;
                    const int sl = ((kk * 4 + lg) - (n & 7)) & 7;
                    uf[nf][kk] = *reinterpret_cast<const short8*>(
                        (const char*)Us + n * 128 + sl * 16);
                }
            #pragma unroll
            for (int mf = 0; mf < 2; mf++)
                #pragma unroll
                for (int nf = 0; nf < 2; nf++)
                    #pragma unroll
                    for (int kk = 0; kk < 2; kk++)
                        accu[mf][nf] = __builtin_amdgcn_mfma_f32_16x16x32_bf16(
                            af[mf][kk], uf[nf][kk], accu[mf][nf], 0, 0, 0);
        }
        __syncthreads();
    }

    const int r4 = (lane >> 4) * 4;
    const int cl = lane & 15;
    const int ccol = z * c_z_col;
    #pragma unroll
    for (int mf = 0; mf < 2; mf++) {
        #pragma unroll
        for (int nf = 0; nf < 2; nf++) {
            #pragma unroll
            for (int j = 0; j < 4; j++) {
                const int row = m0 + wr + mf * 16 + r4 + j;
                const int col = ccol + n0 + wc + nf * 16 + cl;
                if constexpr (GATED) {
                    const float g = accg[mf][nf][j];
                    const float u = accu[mf][nf][j];
                    const float sv =
                        scale ? scale[(size_t)row * scale_stride + z] : 1.0f;
                    const float h = (g / (1.0f + __expf(-g))) * u * sv;
                    C16[(size_t)row * ldc + col] = f2bf(h);
                } else if (atomic_flag) {
                    atomicAdd(&Cf[(size_t)row * ldc + col], accg[mf][nf][j]);
                } else {
                    Cf[(size_t)row * ldc + col] = accg[mf][nf][j];
                }
            }
        }
    }
}

// ---------------------------------------------------------------------------
// Sparse MoE w13: per expert e, gathered tokens idx[e][0..cnt), A-rows via
// per-lane gload16 gather; out heC[e][slot][512] = silu(g)*u*combine.
// ---------------------------------------------------------------------------
__global__ __launch_bounds__(256) void moe_w13_kernel(
    const ushort* __restrict__ Ah, const ushort* __restrict__ w13T,
    ushort* __restrict__ heC, const float* __restrict__ combine,
    const int* __restrict__ counts, const int* __restrict__ idx)
{
    const int e = blockIdx.z;
    const int cnt = counts[e];
    const int m0 = blockIdx.y * 64;
    if (m0 >= cnt) return;
    const int n0 = blockIdx.x * 64;

    __shared__ __align__(16) ushort As[64 * 64];
    __shared__ __align__(16) ushort Bs[64 * 64];
    __shared__ __align__(16) ushort Us[64 * 64];

    const ushort* Bz = w13T + (size_t)e * (2 * kIMoe) * kH;   // [1024][1024]
    const int* idxe = idx + e * kT;
    const int tid = threadIdx.x;
    const int arow = tid >> 3;
    const int achk = tid & 7;
    const int lane = tid & 63;
    const int wave = tid >> 6;
    const int wr = (wave >> 1) * 32;
    const int wc = (wave & 1) * 32;
    const int lrow = lane & 15;
    const int lg = lane >> 4;

    // gathered A row tokens for this thread's two staging rows
    int tokA[2];
    #pragma unroll
    for (int c = 0; c < 2; c++) {
        int gl = m0 + c * 32 + arow;
        tokA[c] = idxe[gl < cnt ? gl : cnt - 1];
    }

    f32x4 accg[2][2] = {};
    f32x4 accu[2][2] = {};

    for (int kk0 = 0; kk0 < kH; kk0 += 64) {
        #pragma unroll
        for (int c = 0; c < 2; c++) {
            const int row = c * 32 + arow;
            const int cs = (achk + (row & 7)) & 7;
            gload16(Ah + (size_t)tokA[c] * kH + kk0 + cs * 8,
                    (char*)As + c * 4096 + tid * 16);
            gload16(Bz + (size_t)(n0 + row) * kH + kk0 + cs * 8,
                    (char*)Bs + c * 4096 + tid * 16);
            gload16(Bz + (size_t)(kIMoe + n0 + row) * kH + kk0 + cs * 8,
                    (char*)Us + c * 4096 + tid * 16);
        }
        __syncthreads();

        short8 af[2][2], bfr[2][2], uf[2][2];
        #pragma unroll
        for (int mf = 0; mf < 2; mf++)
            #pragma unroll
            for (int kk = 0; kk < 2; kk++) {
                const int r = wr + mf * 16 + lrow;
                const int sl = ((kk * 4 + lg) - (r & 7)) & 7;
                af[mf][kk] = *reinterpret_cast<const short8*>(
                    (const char*)As + r * 128 + sl * 16);
            }
        #pragma unroll
        for (int nf = 0; nf < 2; nf++)
            #pragma unroll
            for (int kk = 0; kk < 2; kk++) {
                const int n = wc + nf * 16 + lrow;
                const int sl = ((kk * 4 + lg) - (n & 7)) & 7;
                bfr[nf][kk] = *reinterpret_cast<const short8*>(
                    (const char*)Bs + n * 128 + sl * 16);
                uf[nf][kk] = *reinterpret_cast<const short8*>(
                    (const char*)Us + n * 128 + sl * 16);
            }
        #pragma unroll
        for (int mf = 0; mf < 2; mf++)
            #pragma unroll
            for (int nf = 0; nf < 2; nf++)
                #pragma unroll
                for (int kk = 0; kk < 2; kk++) {
                    accg[mf][nf] = __builtin_amdgcn_mfma_f32_16x16x32_bf16(
                        af[mf][kk], bfr[nf][kk], accg[mf][nf], 0, 0, 0);
                    accu[mf][nf] = __builtin_amdgcn_mfma_f32_16x16x32_bf16(
                        af[mf][kk], uf[nf][kk], accu[mf][nf], 0, 0, 0);
                }
        __syncthreads();
    }

    const int r4 = (lane >> 4) * 4;
    const int cl = lane & 15;
    #pragma unroll
    for (int mf = 0; mf < 2; mf++) {
        #pragma unroll
        for (int nf = 0; nf < 2; nf++) {
            #pragma unroll
            for (int j = 0; j < 4; j++) {
                const int gl = m0 + wr + mf * 16 + r4 + j;
                if (gl < cnt) {
                    const int token = idxe[gl];
                    const float sv = combine[(size_t)token * kE + e];
                    const float g = accg[mf][nf][j];
                    const float u = accu[mf][nf][j];
                    const float h = (g / (1.0f + __expf(-g))) * u * sv;
                    heC[((size_t)e * kT + gl) * kIMoe + n0 + wc + nf * 16 + cl] =
                        f2bf(h);
                }
            }
        }
    }
}

// ---------------------------------------------------------------------------
// Sparse MoE w2: A = heC[e] (compact, linear), K=512; scatter-atomicAdd
// into sc[token][n] via idx.
// ---------------------------------------------------------------------------
__global__ __launch_bounds__(256) void moe_w2_kernel(
    const ushort* __restrict__ heC, const ushort* __restrict__ w2T,
    float* __restrict__ sc, const int* __restrict__ counts,
    const int* __restrict__ idx)
{
    const int e = blockIdx.z;
    const int cnt = counts[e];
    const int m0 = blockIdx.y * 64;
    if (m0 >= cnt) return;
    const int n0 = blockIdx.x * 64;

    __shared__ __align__(16) ushort As[64 * 64];
    __shared__ __align__(16) ushort Bs[64 * 64];

    const ushort* Az = heC + (size_t)e * kT * kIMoe;          // [cnt][512]
    const ushort* Bz = w2T + (size_t)e * kH * kIMoe;          // [1024][512]
    const int* idxe = idx + e * kT;
    const int tid = threadIdx.x;
    const int arow = tid >> 3;
    const int achk = tid & 7;
    const int lane = tid & 63;
    const int wave = tid >> 6;
    const int wr = (wave >> 1) * 32;
    const int wc = (wave & 1) * 32;
    const int lrow = lane & 15;
    const int lg = lane >> 4;

    f32x4 acc[2][2] = {};

    for (int kk0 = 0; kk0 < kIMoe; kk0 += 64) {
        #pragma unroll
        for (int c = 0; c < 2; c++) {
            const int row = c * 32 + arow;
            const int cs = (achk + (row & 7)) & 7;
            gload16(Az + (size_t)(m0 + row) * kIMoe + kk0 + cs * 8,
                    (char*)As + c * 4096 + tid * 16);
            gload16(Bz + (size_t)(n0 + row) * kIMoe + kk0 + cs * 8,
                    (char*)Bs + c * 4096 + tid * 16);
        }
        __syncthreads();

        short8 af[2][2], bfr[2][2];
        #pragma unroll
        for (int mf = 0; mf < 2; mf++)
            #pragma unroll
            for (int kk = 0; kk < 2; kk++) {
                const int r = wr + mf * 16 + lrow;
                const int sl = ((kk * 4 + lg) - (r & 7)) & 7;
                af[mf][kk] = *reinterpret_cast<const short8*>(
                    (const char*)As + r * 128 + sl * 16);
            }
        #pragma unroll
        for (int nf = 0; nf < 2; nf++)
            #pragma unroll
            for (int kk = 0; kk < 2; kk++) {
                const int n = wc + nf * 16 + lrow;
                const int sl = ((kk * 4 + lg) - (n & 7)) & 7;
                bfr[nf][kk] = *reinterpret_cast<const short8*>(
                    (const char*)Bs + n * 128 + sl * 16);
            }
        #pragma unroll
        for (int mf = 0; mf < 2; mf++)
            #pragma unroll
            for (int nf = 0; nf < 2; nf++)
                #pragma unroll
                for (int kk = 0; kk < 2; kk++)
                    acc[mf][nf] = __builtin_amdgcn_mfma_f32_16x16x32_bf16(
                        af[mf][kk], bfr[nf][kk], acc[mf][nf], 0, 0, 0);
        __syncthreads();
    }

    const int r4 = (lane >> 4) * 4;
    const int cl = lane & 15;
    #pragma unroll
    for (int mf = 0; mf < 2; mf++) {
        #pragma unroll
        for (int nf = 0; nf < 2; nf++) {
            #pragma unroll
            for (int j = 0; j < 4; j++) {
                const int gl = m0 + wr + mf * 16 + r4 + j;
                if (gl < cnt) {
                    const int token = idxe[gl];
                    atomicAdd(&sc[(size_t)token * kH + n0 + wc + nf * 16 + cl],
                              acc[mf][nf][j]);
                }
            }
        }
    }
}

// ---------------------------------------------------------------------------
// RoPE + bf16 pack: Qb [16][T][64] (scaled by D^-0.5) and Kb [4][T][64]
// ---------------------------------------------------------------------------
__global__ __launch_bounds__(256) void rope_pack_kernel(
    const float* __restrict__ qkv, const int* __restrict__ positions,
    ushort* __restrict__ Qb, ushort* __restrict__ Kb)
{
    const int t = blockIdx.x;
    const float pos = (float)positions[t];
    for (int item = threadIdx.x; item < (kNQ + kNKV) * 32; item += 256) {
        const int head = item >> 5;
        const int i = item & 31;
        const float inv_freq = powf(10000.0f, -(float)i * (1.0f / 32.0f));
        const float f = pos * inv_freq;
        float sv, cv;
        sincosf(f, &sv, &cv);
        const size_t off = (size_t)t * kQKV + head * kD;
        const float x1 = qkv[off + i];
        const float x2 = qkv[off + 32 + i];
        const float r1 = x1 * cv - x2 * sv;
        const float r2 = x2 * cv + x1 * sv;
        if (head < kNQ) {
            ushort* q = Qb + ((size_t)head * kT + t) * kD;
            q[i] = f2bf(r1 * 0.125f);
            q[i + 32] = f2bf(r2 * 0.125f);
        } else {
            ushort* k = Kb + ((size_t)(head - kNQ) * kT + t) * kD;
            k[i] = f2bf(r1);
            k[i + 32] = f2bf(r2);
        }
    }
}

// ---------------------------------------------------------------------------
// Router: softmax top-2 -> combine (T x 8) + per-expert token lists
// ---------------------------------------------------------------------------
__global__ __launch_bounds__(64) void gate_topk_kernel(
    const float* __restrict__ h, const float* __restrict__ gate_w,
    float* __restrict__ combine, int* __restrict__ counts, int* __restrict__ idx)
{
    const int t = blockIdx.x;
    const int lane = threadIdx.x;
    float acc[kE] = {};
    for (int i = lane; i < kH; i += 64) {
        const float xv = h[(size_t)t * kH + i];
        const float* gw = gate_w + (size_t)i * kE;
        #pragma unroll
        for (int e = 0; e < kE; e++) acc[e] += xv * gw[e];
    }
    #pragma unroll
    for (int e = 0; e < kE; e++) {
        #pragma unroll
        for (int off = 32; off > 0; off >>= 1) acc[e] += __shfl_down(acc[e], off);
    }
    if (lane == 0) {
        float mx = acc[0];
        #pragma unroll
        for (int e = 1; e < kE; e++) mx = fmaxf(mx, acc[e]);
        float p[kE];
        float s = 0.0f;
        #pragma unroll
        for (int e = 0; e < kE; e++) { p[e] = expf(acc[e] - mx); s += p[e]; }
        const float invs = 1.0f / s;
        #pragma unroll
        for (int e = 0; e < kE; e++) p[e] *= invs;
        int i1 = 0;
        #pragma unroll
        for (int e = 1; e < kE; e++) if (p[e] > p[i1]) i1 = e;
        int i2 = (i1 == 0) ? 1 : 0;
        #pragma unroll
        for (int e = 0; e < kE; e++) if (e != i1 && p[e] > p[i2]) i2 = e;
        float outv[kE];
        #pragma unroll
        for (int e = 0; e < kE; e++) outv[e] = 0.0f;
        outv[i1] = p[i1];
        outv[i2] = p[i2];
        #pragma unroll
        for (int e = 0; e < kE; e++) combine[(size_t)t * kE + e] = outv[e];
        const int s1 = atomicAdd(&counts[i1], 1);
        idx[i1 * kT + s1] = t;
        const int s2 = atomicAdd(&counts[i2], 1);
        idx[i2 * kT + s2] = t;
    }
}

// ---------------------------------------------------------------------------
// MFMA flash attention (XOR-swizzled LDS, S^T=mfma(K,Q)) — unchanged
// ---------------------------------------------------------------------------
__global__ __launch_bounds__(256) void attn_mfma_kernel(
    const ushort* __restrict__ Qb, const ushort* __restrict__ Kb,
    const ushort* __restrict__ Vt, ushort* __restrict__ attn_o)
{
    __shared__ __align__(16) ushort Qs[64 * 64];
    __shared__ __align__(16) ushort Ks[64 * 64];
    __shared__ __align__(16) ushort Vs[64 * 64];
    __shared__ __align__(16) ushort Ps[64 * 64];
    const int tid = threadIdx.x;
    const int qb = blockIdx.x * 64;
    const int hq = blockIdx.y;
    const int kvh = hq >> 2;
    const int lane = tid & 63;
    const int wave = tid >> 6;
    const int lrow = lane & 15;
    const int g = lane >> 4;
    const int srow = tid >> 3;
    const int sx = tid & 7;
    const ushort* Qg = Qb + ((size_t)hq * kT + qb) * kD;
    const ushort* Kg = Kb + (size_t)kvh * kT * kD;
    const ushort* Vg = Vt + (size_t)kvh * kD * kT;
    const int xr = (lrow & 7) << 4;

    #pragma unroll
    for (int c = 0; c < 2; c++) {
        const int row = c * 32 + srow;
        gload16(Qg + (size_t)row * kD + ((sx ^ (row & 7)) * 8),
                (char*)Qs + c * 4096 + tid * 16);
    }
    __syncthreads();
    short8 qf[2];
    #pragma unroll
    for (int kk = 0; kk < 2; kk++)
        qf[kk] = *reinterpret_cast<const short8*>(
            (const char*)Qs + (16 * wave + lrow) * 128 + ((kk * 64 + g * 16) ^ xr));

    f32x4 oacc[4] = {};
    float mrow = -1e30f, lsum = 0.0f;

    for (int s0 = 0; s0 <= qb; s0 += 64) {
        __syncthreads();
        #pragma unroll
        for (int c = 0; c < 2; c++) {
            const int row = c * 32 + srow;
            gload16(Kg + (size_t)(s0 + row) * kD + ((sx ^ (row & 7)) * 8),
                    (char*)Ks + c * 4096 + tid * 16);
            gload16(Vg + (size_t)row * kT + s0 + ((sx ^ (row & 7)) * 8),
                    (char*)Vs + c * 4096 + tid * 16);
        }
        __syncthreads();

        f32x4 sacc[4] = {};
        #pragma unroll
        for (int nf = 0; nf < 4; nf++) {
            #pragma unroll
            for (int kk = 0; kk < 2; kk++) {
                short8 kf = *reinterpret_cast<const short8*>(
                    (const char*)Ks + (nf * 16 + lrow) * 128 + ((kk * 64 + g * 16) ^ xr));
                sacc[nf] = __builtin_amdgcn_mfma_f32_16x16x32_bf16(
                    kf, qf[kk], sacc[nf], 0, 0, 0);
            }
        }

        const bool diag = (s0 == qb);
        float pv[16];
        float mloc = -1e30f;
        #pragma unroll
        for (int nf = 0; nf < 4; nf++)
            #pragma unroll
            for (int j = 0; j < 4; j++) {
                float s = sacc[nf][j];
                if (diag && (nf * 16 + g * 4 + j > 16 * wave + lrow)) s = -1e30f;
                pv[nf * 4 + j] = s;
                mloc = fmaxf(mloc, s);
            }
        mloc = fmaxf(mloc, __shfl_xor(mloc, 16));
        mloc = fmaxf(mloc, __shfl_xor(mloc, 32));
        const float mnew = fmaxf(mrow, mloc);
        const float alpha = __expf(mrow - mnew);
        float psum = 0.0f;
        #pragma unroll
        for (int j = 0; j < 16; j++) { pv[j] = __expf(pv[j] - mnew); psum += pv[j]; }
        psum += __shfl_xor(psum, 16);
        psum += __shfl_xor(psum, 32);
        lsum = lsum * alpha + psum;
        mrow = mnew;

        const int prow = 16 * wave + lrow;
        #pragma unroll
        for (int nf = 0; nf < 4; nf++)
            #pragma unroll
            for (int jp = 0; jp < 2; jp++) {
                uint32_t pk = (uint32_t)f2bf(pv[nf * 4 + jp * 2]) |
                              ((uint32_t)f2bf(pv[nf * 4 + jp * 2 + 1]) << 16);
                *reinterpret_cast<uint32_t*>(
                    (char*)Ps + prow * 128 + ((nf * 32 + g * 8 + jp * 4) ^ xr)) = pk;
            }

        float aj[4];
        #pragma unroll
        for (int j = 0; j < 4; j++) aj[j] = __shfl(alpha, g * 4 + j);
        #pragma unroll
        for (int nf = 0; nf < 4; nf++)
            #pragma unroll
            for (int j = 0; j < 4; j++) oacc[nf][j] *= aj[j];

        short8 paf[2];
        #pragma unroll
        for (int kk = 0; kk < 2; kk++)
            paf[kk] = *reinterpret_cast<const short8*>(
                (const char*)Ps + prow * 128 + ((kk * 64 + g * 16) ^ xr));
        #pragma unroll
        for (int nf = 0; nf < 4; nf++)
            #pragma unroll
            for (int kk = 0; kk < 2; kk++) {
                short8 vf = *reinterpret_cast<const short8*>(
                    (const char*)Vs + (nf * 16 + lrow) * 128 + ((kk * 64 + g * 16) ^ xr));
                oacc[nf] = __builtin_amdgcn_mfma_f32_16x16x32_bf16(
                    paf[kk], vf, oacc[nf], 0, 0, 0);
            }
    }

    float lj[4];
    #pragma unroll
    for (int j = 0; j < 4; j++) lj[j] = 1.0f / __shfl(lsum, g * 4 + j);
    #pragma unroll
    for (int nf = 0; nf < 4; nf++)
        #pragma unroll
        for (int j = 0; j < 4; j++) {
            const int trow = qb + 16 * wave + g * 4 + j;
            attn_o[(size_t)trow * (kNQ * kD) + hq * kD + nf * 16 + lrow] =
                f2bf(oacc[nf][j] * lj[j]);
        }
}

__global__ __launch_bounds__(256) void final_out_kernel(
    const float* __restrict__ mlp, const float* __restrict__ shortcut,
    const float* __restrict__ r, float* __restrict__ out)
{
    const int i = blockIdx.x * 256 + threadIdx.x;
    float4 a = reinterpret_cast<const float4*>(mlp)[i];
    float4 b = reinterpret_cast<const float4*>(shortcut)[i];
    reinterpret_cast<float4*>(out)[i] =
        make_float4(a.x + b.x, a.y + b.y, a.z + b.z, a.w + b.w);
    reinterpret_cast<float4*>(out + (size_t)kT * kH)[i] =
        reinterpret_cast<const float4*>(r)[i];
}

}  // namespace

extern "C" void kernel_launch(void* const* d_in, const int* in_sizes, int n_in,
                              void* d_out, int out_size, void* d_ws, size_t ws_size,
                              hipStream_t stream) {
    (void)in_sizes; (void)n_in; (void)out_size; (void)ws_size;
    const float* hidden   = (const float*)d_in[0];
    const float* residual = (const float*)d_in[1];
    const int*   positions= (const int*)d_in[2];
    const float* ln0_w    = (const float*)d_in[3];
    const float* pa0_w    = (const float*)d_in[4];
    const float* ln1_w    = (const float*)d_in[5];
    const float* pa1_w    = (const float*)d_in[6];
    const float* qkv0_w   = (const float*)d_in[7];
    const float* o0_w     = (const float*)d_in[8];
    const float* qkv1_w   = (const float*)d_in[9];
    const float* o1_w     = (const float*)d_in[10];
    const float* gu0_w    = (const float*)d_in[11];
    const float* dn0_w    = (const float*)d_in[12];
    const float* gu1_w    = (const float*)d_in[13];
    const float* dn1_w    = (const float*)d_in[14];
    const float* gate_w   = (const float*)d_in[15];
    const float* w13      = (const float*)d_in[16];
    const float* w2       = (const float*)d_in[17];
    float* out_h = (float*)d_out;

    char* wsb = (char*)d_ws;
    float*  r_buf   = (float*)(wsb + (0ull  << 20));   // 4 MB
    float*  h32     = (float*)(wsb + (4ull  << 20));   // 4 MB
    float*  t0_buf  = (float*)(wsb + (8ull  << 20));   // 4 MB
    float*  qkv_buf = (float*)(wsb + (12ull << 20));   // 6 MB
    float*  sc_buf  = (float*)(wsb + (18ull << 20));   // 4 MB
    float*  cb_buf  = (float*)(wsb + (22ull << 20));   // 32 KB combine
    int*    cnt_buf = (int*)  (wsb + (22ull << 20) + (1 << 15));  // 32 B
    int*    idx_buf = (int*)  (wsb + (22ull << 20) + (1 << 16));  // 32 KB
    ushort* h16     = (ushort*)(wsb + (23ull << 20));  // 2 MB
    ushort* ao16    = (ushort*)(wsb + (25ull << 20));  // 2 MB
    ushort* heC     = (ushort*)(wsb + (27ull << 20));  // 8 MB ([8][1024][512])
    ushort* wT      = (ushort*)(wsb + (35ull << 20));  // 16 MB (ends 51 MB)
    ushort* Qb      = (ushort*)(wsb + (40ull << 20));  // 2 MB (aliases wT tail)
    ushort* Kb      = (ushort*)(wsb + (42ull << 20));  // 0.5 MB
    ushort* VtG     = (ushort*)(wsb + (43ull << 20));  // 0.5 MB

    auto transp = [&](const float* W, int R, int Cn, int nz, long zs_in, long zs_out) {
        transpose_bf16_kernel<<<dim3(Cn / 64, R / 64, nz), 256, 0, stream>>>(
            W, wT, R, Cn, Cn, zs_in, zs_out);
    };
    auto gemm_f32 = [&](const ushort* A, float* C, int N, int lda_,
                        int ldb_, int ldc_, int nz, int kc, int kzoff, int atomic) {
        mgemm_kernel<false><<<dim3(N / 64, kT / 64, nz), 256, 0, stream>>>(
            A, wT, C, nullptr, nullptr, lda_, ldb_, ldc_, kc,
            0, 0, 0, kzoff, 0, atomic);
    };
    auto attention = [&](const float* qkv_w, const float* o_w) {
        transp(qkv_w, kH, kQKV, 1, 0, 0);
        gemm_f32(h16, qkv_buf, kQKV, kH, kH, kQKV, 1, kH, 0, 0);
        rope_pack_kernel<<<kT, 256, 0, stream>>>(qkv_buf, positions, Qb, Kb);
        transpose_bf16_kernel<<<dim3(1, kT / 64, kNKV), 256, 0, stream>>>(
            qkv_buf + (kNQ + kNKV) * kD, VtG, kT, kD, kQKV, kD, (long)kD * kT);
        attn_mfma_kernel<<<dim3(kT / 64, kNQ), 256, 0, stream>>>(Qb, Kb, VtG, ao16);
        transp(o_w, kNQ * kD, kH, 1, 0, 0);
        hipMemsetAsync(t0_buf, 0, (size_t)kT * kH * 4, stream);
        gemm_f32(ao16, t0_buf, kH, kNQ * kD, kNQ * kD, kH, 2, 512, 512, 1);
    };
    auto dense_mlp = [&](const float* gu_w, const float* dn_w) {
        transp(gu_w, kH, 2 * kIDense, 1, 0, 0);
        mgemm_kernel<true><<<dim3(kIDense / 64, kT / 64, 1), 256, 0, stream>>>(
            h16, wT, nullptr, (ushort*)heC, nullptr, kH, kH, kIDense, kH,
            kIDense, 0, 0, 0, 0, 0);
        transp(dn_w, kIDense, kH, 1, 0, 0);
        hipMemsetAsync(t0_buf, 0, (size_t)kT * kH * 4, stream);
        gemm_f32((ushort*)heC, t0_buf, kH, kIDense, kIDense, kH, 4, 1024, 1024, 1);
    };

    // h, r = add_rmsnorm(hidden, residual, ln0)
    add_rmsnorm_kernel<<<kT, 256, 0, stream>>>(hidden, residual, ln0_w, h32, h16, r_buf);
    // h = attention0(h) -> t0
    attention(qkv0_w, o0_w);
    // h, r = add_rmsnorm(t0, r, pa0)
    add_rmsnorm_kernel<<<kT, 256, 0, stream>>>(t0_buf, r_buf, pa0_w, h32, h16, r_buf);
    // shortcut = moe(h), SPARSE top-2
    hipMemsetAsync(cnt_buf, 0, kE * sizeof(int), stream);
    gate_topk_kernel<<<kT, 64, 0, stream>>>(h32, gate_w, cb_buf, cnt_buf, idx_buf);
    transp(w13, kH, 2 * kIMoe, kE, (long)kH * 2 * kIMoe, (long)kH * 2 * kIMoe);
    moe_w13_kernel<<<dim3(kIMoe / 64, kT / 64, kE), 256, 0, stream>>>(
        h16, wT, heC, cb_buf, cnt_buf, idx_buf);
    transpose_bf16_kernel<<<dim3(kH / 64, kIMoe / 64, kE), 256, 0, stream>>>(
        w2, wT, kIMoe, kH, kH, (long)kIMoe * kH, (long)kH * kIMoe);
    hipMemsetAsync(sc_buf, 0, (size_t)kT * kH * 4, stream);
    moe_w2_kernel<<<dim3(kH / 64, kT / 64, kE), 256, 0, stream>>>(
        heC, wT, sc_buf, cnt_buf, idx_buf);
    // h = dense_mlp0(h) -> t0
    dense_mlp(gu0_w, dn0_w);
    // h, r = add_rmsnorm(t0, r, ln1)
    add_rmsnorm_kernel<<<kT, 256, 0, stream>>>(t0_buf, r_buf, ln1_w, h32, h16, r_buf);
    // h = attention1(h) -> t0
    attention(qkv1_w, o1_w);
    // h, r = add_rmsnorm(t0, r, pa1)
    add_rmsnorm_kernel<<<kT, 256, 0, stream>>>(t0_buf, r_buf, pa1_w, h32, h16, r_buf);
    // h = dense_mlp1(h) -> t0
    dense_mlp(gu1_w, dn1_w);
    // out = (t0 + shortcut, r)
    final_out_kernel<<<(kT * kH / 4) / 256, 256, 0, stream>>>(t0_buf, sc_buf, r_buf, out_h);
}

// Round 11
// 345.047 us; speedup vs baseline: 1.1253x; 1.1253x over previous
//
#include <hip/hip_runtime.h>
#include <math.h>

namespace {

constexpr int kT = 1024;
constexpr int kH = 1024;
constexpr int kNQ = 16;
constexpr int kNKV = 4;
constexpr int kD = 64;
constexpr int kQKV = (kNQ + 2 * kNKV) * kD;   // 1536
constexpr int kIDense = 4096;
constexpr int kIMoe = 512;
constexpr int kE = 8;
constexpr float kEps = 1e-6f;
constexpr long kTH = (long)kT * kH;

typedef __attribute__((ext_vector_type(8))) short short8;
typedef __attribute__((ext_vector_type(4))) float f32x4;

__device__ __forceinline__ ushort f2bf(float f) {
    union { float f; uint32_t u; } v; v.f = f;
    uint32_t r = (v.u + 0x7fffu + ((v.u >> 16) & 1u)) >> 16;
    return (ushort)r;
}
__device__ __forceinline__ void gload16(const void* g, void* l) {
    __builtin_amdgcn_global_load_lds(
        (const __attribute__((address_space(1))) void*)g,
        (__attribute__((address_space(3))) void*)l, 16, 0, 0);
}

// ---------------------------------------------------------------------------
// add + RMSNorm with fused nparts-sum:
//   x = sum_{p<nparts} xP[p*kTH + .]; r_out = x + res; h = rmsnorm(r_out)*w
// ---------------------------------------------------------------------------
__global__ __launch_bounds__(256) void add_rmsnorm_kernel(
    const float* __restrict__ xP, int nparts, const float* __restrict__ res,
    const float* __restrict__ w, float* __restrict__ h32,
    ushort* __restrict__ h16, float* __restrict__ r_out)
{
    __shared__ float red[4];
    const int t = blockIdx.x;
    const int i = threadIdx.x;
    const size_t base = (size_t)t * kH;
    float4 s = reinterpret_cast<const float4*>(res + base)[i];
    for (int p = 0; p < nparts; p++) {
        float4 a = reinterpret_cast<const float4*>(xP + p * kTH + base)[i];
        s.x += a.x; s.y += a.y; s.z += a.z; s.w += a.w;
    }
    reinterpret_cast<float4*>(r_out + base)[i] = s;
    float ss = s.x * s.x + s.y * s.y + s.z * s.z + s.w * s.w;
    #pragma unroll
    for (int off = 32; off > 0; off >>= 1) ss += __shfl_down(ss, off);
    if ((i & 63) == 0) red[i >> 6] = ss;
    __syncthreads();
    const float tot = red[0] + red[1] + red[2] + red[3];
    const float inv = rsqrtf(tot * (1.0f / kH) + kEps);
    float4 wv = reinterpret_cast<const float4*>(w)[i];
    float4 o = make_float4(s.x * inv * wv.x, s.y * inv * wv.y,
                           s.z * inv * wv.z, s.w * inv * wv.w);
    reinterpret_cast<float4*>(h32 + base)[i] = o;
    ushort4 u;
    u.x = f2bf(o.x); u.y = f2bf(o.y); u.z = f2bf(o.z); u.w = f2bf(o.w);
    reinterpret_cast<ushort4*>(h16 + base)[i] = u;
}

// ---------------------------------------------------------------------------
// Fast transpose + f32 -> bf16: W (R x Cn f32, row stride ld_w) -> WT (Cn x R).
// ---------------------------------------------------------------------------
__global__ __launch_bounds__(256) void transpose_bf16_kernel(
    const float* __restrict__ W, ushort* __restrict__ WT,
    int R, int Cn, int ld_w, long w_z_stride, long wt_z_stride)
{
    __shared__ float tile[64 * 65];
    const int z = blockIdx.z;
    const float* Wz = W + (size_t)z * w_z_stride;
    ushort* WTz = WT + (size_t)z * wt_z_stride;
    const int r0 = blockIdx.y * 64;
    const int c0 = blockIdx.x * 64;
    const int tid = threadIdx.x;
    const int lr = tid >> 4;
    const int lc = (tid & 15) * 4;
    #pragma unroll
    for (int p = 0; p < 4; p++) {
        const int row = p * 16 + lr;
        float4 v = *reinterpret_cast<const float4*>(
            &Wz[(size_t)(r0 + row) * ld_w + c0 + lc]);
        tile[row * 65 + lc + 0] = v.x;
        tile[row * 65 + lc + 1] = v.y;
        tile[row * 65 + lc + 2] = v.z;
        tile[row * 65 + lc + 3] = v.w;
    }
    __syncthreads();
    const int ocl = tid >> 2;
    const int q = tid & 3;
    ushort u[16];
    #pragma unroll
    for (int e = 0; e < 16; e++)
        u[e] = f2bf(tile[(q * 16 + e) * 65 + ocl]);
    ushort* dst = &WTz[(size_t)(c0 + ocl) * R + r0 + q * 16];
    *reinterpret_cast<short8*>(dst) = *reinterpret_cast<short8*>(&u[0]);
    *reinterpret_cast<short8*>(dst + 8) = *reinterpret_cast<short8*>(&u[8]);
}

// ---------------------------------------------------------------------------
// bf16 MFMA GEMM, 64x64 tile, BK=64, 256 thr (4 waves, 2x2 frags).
// Both operands bf16 via global_load_lds, source-chunk skewed.
// XCD-aware swizzle: fid -> (fid&7)*nf/8 + fid>>3, decomposed m-fastest so
// the blocks sharing a B-panel (same n0) are contiguous on one XCD.
// Split-K: z plain-stores into Cf + z*c_fstride (no atomics).
// ---------------------------------------------------------------------------
template <bool GATED>
__global__ __launch_bounds__(256) void mgemm_kernel(
    const ushort* __restrict__ A, const ushort* __restrict__ B,
    float* __restrict__ Cf, ushort* __restrict__ C16,
    const float* __restrict__ scale,
    int lda, int ldb, int ldc, int kc,
    int gate_off_rows, long b_z_stride, int c_z_col, int k_z_off,
    int scale_stride, long c_fstride)
{
    __shared__ __align__(16) ushort As[64 * 64];
    __shared__ __align__(16) ushort Bs[64 * 64];
    __shared__ __align__(16) ushort Us[GATED ? 64 * 64 : 8];

    const int z = blockIdx.z;
    // ---- XCD swizzle (gx*gy is a multiple of 8 for every launch here)
    const int gy = gridDim.y;
    const int nf = gridDim.x * gy;
    const int fid = blockIdx.x + gridDim.x * blockIdx.y;
    const int qq = nf >> 3;
    const int id2 = (fid & 7) * qq + (fid >> 3);
    const int m0 = (id2 % gy) * 64;
    const int n0 = (id2 / gy) * 64;

    const int tid = threadIdx.x;
    const ushort* Bz = B + (size_t)z * b_z_stride;
    const int k0 = z * k_z_off;

    const int arow = tid >> 3;
    const int achk = tid & 7;

    const int lane = tid & 63;
    const int wave = tid >> 6;
    const int wr = (wave >> 1) * 32;
    const int wc = (wave & 1) * 32;
    const int lrow = lane & 15;
    const int lg = lane >> 4;

    f32x4 accg[2][2] = {};
    f32x4 accu[2][2] = {};

    for (int kk0 = 0; kk0 < kc; kk0 += 64) {
        const int kbase = k0 + kk0;
        #pragma unroll
        for (int c = 0; c < 2; c++) {
            const int row = c * 32 + arow;
            const int cs = (achk + (row & 7)) & 7;
            gload16(A + (size_t)(m0 + row) * lda + kbase + cs * 8,
                    (char*)As + c * 4096 + tid * 16);
            gload16(Bz + (size_t)(n0 + row) * ldb + kbase + cs * 8,
                    (char*)Bs + c * 4096 + tid * 16);
            if constexpr (GATED)
                gload16(Bz + (size_t)(gate_off_rows + n0 + row) * ldb + kbase + cs * 8,
                        (char*)Us + c * 4096 + tid * 16);
        }
        __syncthreads();

        short8 af[2][2], bfr[2][2];
        #pragma unroll
        for (int mf = 0; mf < 2; mf++)
            #pragma unroll
            for (int kk = 0; kk < 2; kk++) {
                const int r = wr + mf * 16 + lrow;
                const int sl = ((kk * 4 + lg) - (r & 7)) & 7;
                af[mf][kk] = *reinterpret_cast<const short8*>(
                    (const char*)As + r * 128 + sl * 16);
            }
        #pragma unroll
        for (int nf2 = 0; nf2 < 2; nf2++)
            #pragma unroll
            for (int kk = 0; kk < 2; kk++) {
                const int n = wc + nf2 * 16 + lrow;
                const int sl = ((kk * 4 + lg) - (n & 7)) & 7;
                bfr[nf2][kk] = *reinterpret_cast<const short8*>(
                    (const char*)Bs + n * 128 + sl * 16);
            }
        #pragma unroll
        for (int mf = 0; mf < 2; mf++)
            #pragma unroll
            for (int nf2 = 0; nf2 < 2; nf2++)
                #pragma unroll
                for (int kk = 0; kk < 2; kk++)
                    accg[mf][nf2] = __builtin_amdgcn_mfma_f32_16x16x32_bf16(
                        af[mf][kk], bfr[nf2][kk], accg[mf][nf2], 0, 0, 0);
        if constexpr (GATED) {
            short8 uf[2][2];
            #pragma unroll
            for (int nf2 = 0; nf2 < 2; nf2++)
                #pragma unroll
                for (int kk = 0; kk < 2; kk++) {
                    const int n = wc + nf2 * 16 + lrow;
                    const int sl = ((kk * 4 + lg) - (n & 7)) & 7;
                    uf[nf2][kk] = *reinterpret_cast<const short8*>(
                        (const char*)Us + n * 128 + sl * 16);
                }
            #pragma unroll
            for (int mf = 0; mf < 2; mf++)
                #pragma unroll
                for (int nf2 = 0; nf2 < 2; nf2++)
                    #pragma unroll
                    for (int kk = 0; kk < 2; kk++)
                        accu[mf][nf2] = __builtin_amdgcn_mfma_f32_16x16x32_bf16(
                            af[mf][kk], uf[nf2][kk], accu[mf][nf2], 0, 0, 0);
        }
        __syncthreads();
    }

    // epilogue — C/D layout: col = lane&15, row = (lane>>4)*4 + j
    const int r4 = (lane >> 4) * 4;
    const int cl = lane & 15;
    const int ccol = z * c_z_col;
    float* Cfz = Cf ? Cf + (size_t)z * c_fstride : nullptr;
    #pragma unroll
    for (int mf = 0; mf < 2; mf++) {
        #pragma unroll
        for (int nf2 = 0; nf2 < 2; nf2++) {
            #pragma unroll
            for (int j = 0; j < 4; j++) {
                const int row = m0 + wr + mf * 16 + r4 + j;
                const int col = ccol + n0 + wc + nf2 * 16 + cl;
                if constexpr (GATED) {
                    const float g = accg[mf][nf2][j];
                    const float u = accu[mf][nf2][j];
                    const float sv =
                        scale ? scale[(size_t)row * scale_stride + z] : 1.0f;
                    const float h = (g / (1.0f + __expf(-g))) * u * sv;
                    C16[(size_t)row * ldc + col] = f2bf(h);
                } else {
                    Cfz[(size_t)row * ldc + col] = accg[mf][nf2][j];
                }
            }
        }
    }
}

// ---------------------------------------------------------------------------
// RoPE + bf16 pack: Qb [16][T][64] (scaled by D^-0.5) and Kb [4][T][64]
// ---------------------------------------------------------------------------
__global__ __launch_bounds__(256) void rope_pack_kernel(
    const float* __restrict__ qkv, const int* __restrict__ positions,
    ushort* __restrict__ Qb, ushort* __restrict__ Kb)
{
    const int t = blockIdx.x;
    const float pos = (float)positions[t];
    for (int item = threadIdx.x; item < (kNQ + kNKV) * 32; item += 256) {
        const int head = item >> 5;
        const int i = item & 31;
        const float inv_freq = powf(10000.0f, -(float)i * (1.0f / 32.0f));
        const float f = pos * inv_freq;
        float sv, cv;
        sincosf(f, &sv, &cv);
        const size_t off = (size_t)t * kQKV + head * kD;
        const float x1 = qkv[off + i];
        const float x2 = qkv[off + 32 + i];
        const float r1 = x1 * cv - x2 * sv;
        const float r2 = x2 * cv + x1 * sv;
        if (head < kNQ) {
            ushort* q = Qb + ((size_t)head * kT + t) * kD;
            q[i] = f2bf(r1 * 0.125f);
            q[i + 32] = f2bf(r2 * 0.125f);
        } else {
            ushort* k = Kb + ((size_t)(head - kNQ) * kT + t) * kD;
            k[i] = f2bf(r1);
            k[i + 32] = f2bf(r2);
        }
    }
}

// ---------------------------------------------------------------------------
// Router: logits = h32 @ gate_w, softmax, top-2 -> combine (T x 8)
// ---------------------------------------------------------------------------
__global__ __launch_bounds__(64) void gate_topk_kernel(
    const float* __restrict__ h, const float* __restrict__ gate_w,
    float* __restrict__ combine)
{
    const int t = blockIdx.x;
    const int lane = threadIdx.x;
    float acc[kE] = {};
    for (int i = lane; i < kH; i += 64) {
        const float xv = h[(size_t)t * kH + i];
        const float* gw = gate_w + (size_t)i * kE;
        #pragma unroll
        for (int e = 0; e < kE; e++) acc[e] += xv * gw[e];
    }
    #pragma unroll
    for (int e = 0; e < kE; e++) {
        #pragma unroll
        for (int off = 32; off > 0; off >>= 1) acc[e] += __shfl_down(acc[e], off);
    }
    if (lane == 0) {
        float mx = acc[0];
        #pragma unroll
        for (int e = 1; e < kE; e++) mx = fmaxf(mx, acc[e]);
        float p[kE];
        float s = 0.0f;
        #pragma unroll
        for (int e = 0; e < kE; e++) { p[e] = expf(acc[e] - mx); s += p[e]; }
        const float invs = 1.0f / s;
        #pragma unroll
        for (int e = 0; e < kE; e++) p[e] *= invs;
        int i1 = 0;
        #pragma unroll
        for (int e = 1; e < kE; e++) if (p[e] > p[i1]) i1 = e;
        int i2 = (i1 == 0) ? 1 : 0;
        #pragma unroll
        for (int e = 0; e < kE; e++) if (e != i1 && p[e] > p[i2]) i2 = e;
        float outv[kE];
        #pragma unroll
        for (int e = 0; e < kE; e++) outv[e] = 0.0f;
        outv[i1] = p[i1];
        outv[i2] = p[i2];
        #pragma unroll
        for (int e = 0; e < kE; e++) combine[(size_t)t * kE + e] = outv[e];
    }
}

// ---------------------------------------------------------------------------
// MFMA flash attention (XOR-swizzled LDS, S^T=mfma(K,Q)) — unchanged
// ---------------------------------------------------------------------------
__global__ __launch_bounds__(256) void attn_mfma_kernel(
    const ushort* __restrict__ Qb, const ushort* __restrict__ Kb,
    const ushort* __restrict__ Vt, ushort* __restrict__ attn_o)
{
    __shared__ __align__(16) ushort Qs[64 * 64];
    __shared__ __align__(16) ushort Ks[64 * 64];
    __shared__ __align__(16) ushort Vs[64 * 64];
    __shared__ __align__(16) ushort Ps[64 * 64];
    const int tid = threadIdx.x;
    const int qb = blockIdx.x * 64;
    const int hq = blockIdx.y;
    const int kvh = hq >> 2;
    const int lane = tid & 63;
    const int wave = tid >> 6;
    const int lrow = lane & 15;
    const int g = lane >> 4;
    const int srow = tid >> 3;
    const int sx = tid & 7;
    const ushort* Qg = Qb + ((size_t)hq * kT + qb) * kD;
    const ushort* Kg = Kb + (size_t)kvh * kT * kD;
    const ushort* Vg = Vt + (size_t)kvh * kD * kT;
    const int xr = (lrow & 7) << 4;

    #pragma unroll
    for (int c = 0; c < 2; c++) {
        const int row = c * 32 + srow;
        gload16(Qg + (size_t)row * kD + ((sx ^ (row & 7)) * 8),
                (char*)Qs + c * 4096 + tid * 16);
    }
    __syncthreads();
    short8 qf[2];
    #pragma unroll
    for (int kk = 0; kk < 2; kk++)
        qf[kk] = *reinterpret_cast<const short8*>(
            (const char*)Qs + (16 * wave + lrow) * 128 + ((kk * 64 + g * 16) ^ xr));

    f32x4 oacc[4] = {};
    float mrow = -1e30f, lsum = 0.0f;

    for (int s0 = 0; s0 <= qb; s0 += 64) {
        __syncthreads();
        #pragma unroll
        for (int c = 0; c < 2; c++) {
            const int row = c * 32 + srow;
            gload16(Kg + (size_t)(s0 + row) * kD + ((sx ^ (row & 7)) * 8),
                    (char*)Ks + c * 4096 + tid * 16);
            gload16(Vg + (size_t)row * kT + s0 + ((sx ^ (row & 7)) * 8),
                    (char*)Vs + c * 4096 + tid * 16);
        }
        __syncthreads();

        f32x4 sacc[4] = {};
        #pragma unroll
        for (int nf = 0; nf < 4; nf++) {
            #pragma unroll
            for (int kk = 0; kk < 2; kk++) {
                short8 kf = *reinterpret_cast<const short8*>(
                    (const char*)Ks + (nf * 16 + lrow) * 128 + ((kk * 64 + g * 16) ^ xr));
                sacc[nf] = __builtin_amdgcn_mfma_f32_16x16x32_bf16(
                    kf, qf[kk], sacc[nf], 0, 0, 0);
            }
        }

        const bool diag = (s0 == qb);
        float pv[16];
        float mloc = -1e30f;
        #pragma unroll
        for (int nf = 0; nf < 4; nf++)
            #pragma unroll
            for (int j = 0; j < 4; j++) {
                float s = sacc[nf][j];
                if (diag && (nf * 16 + g * 4 + j > 16 * wave + lrow)) s = -1e30f;
                pv[nf * 4 + j] = s;
                mloc = fmaxf(mloc, s);
            }
        mloc = fmaxf(mloc, __shfl_xor(mloc, 16));
        mloc = fmaxf(mloc, __shfl_xor(mloc, 32));
        const float mnew = fmaxf(mrow, mloc);
        const float alpha = __expf(mrow - mnew);
        float psum = 0.0f;
        #pragma unroll
        for (int j = 0; j < 16; j++) { pv[j] = __expf(pv[j] - mnew); psum += pv[j]; }
        psum += __shfl_xor(psum, 16);
        psum += __shfl_xor(psum, 32);
        lsum = lsum * alpha + psum;
        mrow = mnew;

        const int prow = 16 * wave + lrow;
        #pragma unroll
        for (int nf = 0; nf < 4; nf++)
            #pragma unroll
            for (int jp = 0; jp < 2; jp++) {
                uint32_t pk = (uint32_t)f2bf(pv[nf * 4 + jp * 2]) |
                              ((uint32_t)f2bf(pv[nf * 4 + jp * 2 + 1]) << 16);
                *reinterpret_cast<uint32_t*>(
                    (char*)Ps + prow * 128 + ((nf * 32 + g * 8 + jp * 4) ^ xr)) = pk;
            }

        float aj[4];
        #pragma unroll
        for (int j = 0; j < 4; j++) aj[j] = __shfl(alpha, g * 4 + j);
        #pragma unroll
        for (int nf = 0; nf < 4; nf++)
            #pragma unroll
            for (int j = 0; j < 4; j++) oacc[nf][j] *= aj[j];

        short8 paf[2];
        #pragma unroll
        for (int kk = 0; kk < 2; kk++)
            paf[kk] = *reinterpret_cast<const short8*>(
                (const char*)Ps + prow * 128 + ((kk * 64 + g * 16) ^ xr));
        #pragma unroll
        for (int nf = 0; nf < 4; nf++)
            #pragma unroll
            for (int kk = 0; kk < 2; kk++) {
                short8 vf = *reinterpret_cast<const short8*>(
                    (const char*)Vs + (nf * 16 + lrow) * 128 + ((kk * 64 + g * 16) ^ xr));
                oacc[nf] = __builtin_amdgcn_mfma_f32_16x16x32_bf16(
                    paf[kk], vf, oacc[nf], 0, 0, 0);
            }
    }

    float lj[4];
    #pragma unroll
    for (int j = 0; j < 4; j++) lj[j] = 1.0f / __shfl(lsum, g * 4 + j);
    #pragma unroll
    for (int nf = 0; nf < 4; nf++)
        #pragma unroll
        for (int j = 0; j < 4; j++) {
            const int trow = qb + 16 * wave + g * 4 + j;
            attn_o[(size_t)trow * (kNQ * kD) + hq * kD + nf * 16 + lrow] =
                f2bf(oacc[nf][j] * lj[j]);
        }
}

// ---------------------------------------------------------------------------
// final: out[0:TH] = sum(mlpP[0..3]) + sum(scP[0..3]); out[TH:] = r
// ---------------------------------------------------------------------------
__global__ __launch_bounds__(256) void final_out_kernel(
    const float* __restrict__ mlpP, const float* __restrict__ scP,
    const float* __restrict__ r, float* __restrict__ out)
{
    const int i = blockIdx.x * 256 + threadIdx.x;
    float4 s = make_float4(0.f, 0.f, 0.f, 0.f);
    #pragma unroll
    for (int p = 0; p < 4; p++) {
        float4 a = reinterpret_cast<const float4*>(mlpP + p * kTH)[i];
        float4 b = reinterpret_cast<const float4*>(scP + p * kTH)[i];
        s.x += a.x + b.x; s.y += a.y + b.y; s.z += a.z + b.z; s.w += a.w + b.w;
    }
    reinterpret_cast<float4*>(out)[i] = s;
    reinterpret_cast<float4*>(out + kTH)[i] =
        reinterpret_cast<const float4*>(r)[i];
}

}  // namespace

extern "C" void kernel_launch(void* const* d_in, const int* in_sizes, int n_in,
                              void* d_out, int out_size, void* d_ws, size_t ws_size,
                              hipStream_t stream) {
    (void)in_sizes; (void)n_in; (void)out_size; (void)ws_size;
    const float* hidden   = (const float*)d_in[0];
    const float* residual = (const float*)d_in[1];
    const int*   positions= (const int*)d_in[2];
    const float* ln0_w    = (const float*)d_in[3];
    const float* pa0_w    = (const float*)d_in[4];
    const float* ln1_w    = (const float*)d_in[5];
    const float* pa1_w    = (const float*)d_in[6];
    const float* qkv0_w   = (const float*)d_in[7];
    const float* o0_w     = (const float*)d_in[8];
    const float* qkv1_w   = (const float*)d_in[9];
    const float* o1_w     = (const float*)d_in[10];
    const float* gu0_w    = (const float*)d_in[11];
    const float* dn0_w    = (const float*)d_in[12];
    const float* gu1_w    = (const float*)d_in[13];
    const float* dn1_w    = (const float*)d_in[14];
    const float* gate_w   = (const float*)d_in[15];
    const float* w13      = (const float*)d_in[16];
    const float* w2       = (const float*)d_in[17];
    float* out_h = (float*)d_out;

    char* wsb = (char*)d_ws;
    float*  r_buf   = (float*)(wsb + (0ull  << 20));   // 4 MB
    float*  h32     = (float*)(wsb + (4ull  << 20));   // 4 MB
    float*  t0P     = (float*)(wsb + (8ull  << 20));   // 16 MB (4 split-K parts)
    // cb aliases t0P start: written AFTER pa0 consumes t0P, read by w13 GEMM
    // BEFORE dense_mlp0 rewrites t0P. (r10 bug: cb at 66MB was inside wT.)
    float*  cb_buf  = (float*)(wsb + (8ull  << 20));   // 32 KB (time-disjoint)
    float*  scP     = (float*)(wsb + (24ull << 20));   // 16 MB (4 parts)
    ushort* h16     = (ushort*)(wsb + (40ull << 20));  // 2 MB
    ushort* ao16    = (ushort*)(wsb + (42ull << 20));  // 2 MB
    float*  qkv_buf = (float*)(wsb + (44ull << 20));   // 6 MB (aliases he16)
    ushort* he16    = (ushort*)(wsb + (44ull << 20));  // 8 MB (44..52)
    ushort* wT      = (ushort*)(wsb + (52ull << 20));  // 16 MB (52..68)
    ushort* Qb      = (ushort*)(wsb + (62ull << 20));  // 2 MB (wT tail: only
    ushort* Kb      = (ushort*)(wsb + (64ull << 20));  // 0.5 MB  live while wT
    ushort* VtG     = (ushort*)(wsb + (65ull << 20));  // 0.5 MB  holds 3MB qkv_w^T)

    auto transp = [&](const float* W, int R, int Cn, int nz, long zs_in, long zs_out) {
        transpose_bf16_kernel<<<dim3(Cn / 64, R / 64, nz), 256, 0, stream>>>(
            W, wT, R, Cn, Cn, zs_in, zs_out);
    };
    // split-K parts: each z plain-stores into C + z*kTH
    auto gemm_f32 = [&](const ushort* A, float* C, int N, int lda_,
                        int ldb_, int ldc_, int nz, int kc, int kzoff) {
        mgemm_kernel<false><<<dim3(N / 64, kT / 64, nz), 256, 0, stream>>>(
            A, wT, C, nullptr, nullptr, lda_, ldb_, ldc_, kc,
            0, 0, 0, kzoff, 0, kTH);
    };
    auto attention = [&](const float* qkv_w, const float* o_w) {
        transp(qkv_w, kH, kQKV, 1, 0, 0);
        mgemm_kernel<false><<<dim3(kQKV / 64, kT / 64, 1), 256, 0, stream>>>(
            h16, wT, qkv_buf, nullptr, nullptr, kH, kH, kQKV, kH,
            0, 0, 0, 0, 0, 0);
        rope_pack_kernel<<<kT, 256, 0, stream>>>(qkv_buf, positions, Qb, Kb);
        transpose_bf16_kernel<<<dim3(1, kT / 64, kNKV), 256, 0, stream>>>(
            qkv_buf + (kNQ + kNKV) * kD, VtG, kT, kD, kQKV, kD, (long)kD * kT);
        attn_mfma_kernel<<<dim3(kT / 64, kNQ), 256, 0, stream>>>(Qb, Kb, VtG, ao16);
        transp(o_w, kNQ * kD, kH, 1, 0, 0);
        gemm_f32(ao16, t0P, kH, kNQ * kD, kNQ * kD, kH, 2, 512, 512);
    };
    auto dense_mlp = [&](const float* gu_w, const float* dn_w) {
        transp(gu_w, kH, 2 * kIDense, 1, 0, 0);
        mgemm_kernel<true><<<dim3(kIDense / 64, kT / 64, 1), 256, 0, stream>>>(
            h16, wT, nullptr, he16, nullptr, kH, kH, kIDense, kH,
            kIDense, 0, 0, 0, 0, 0);
        transp(dn_w, kIDense, kH, 1, 0, 0);
        gemm_f32(he16, t0P, kH, kIDense, kIDense, kH, 4, 1024, 1024);
    };

    // h, r = add_rmsnorm(hidden, residual, ln0)
    add_rmsnorm_kernel<<<kT, 256, 0, stream>>>(hidden, 1, residual, ln0_w, h32, h16, r_buf);
    // h = attention0(h) -> t0P[0..1]
    attention(qkv0_w, o0_w);
    // h, r = add_rmsnorm(sum t0P[0..1], r, pa0)
    add_rmsnorm_kernel<<<kT, 256, 0, stream>>>(t0P, 2, r_buf, pa0_w, h32, h16, r_buf);
    // shortcut = moe(h) (dense, combine-scaled) -> scP[0..3]
    gate_topk_kernel<<<kT, 64, 0, stream>>>(h32, gate_w, cb_buf);
    transp(w13, kH, 2 * kIMoe, kE, (long)kH * 2 * kIMoe, (long)kH * 2 * kIMoe);
    mgemm_kernel<true><<<dim3(kIMoe / 64, kT / 64, kE), 256, 0, stream>>>(
        h16, wT, nullptr, he16, cb_buf, kH, kH, kIDense, kH,
        kIMoe, (long)kH * 2 * kIMoe, kIMoe, 0, kE, 0);
    transp(w2, kE * kIMoe, kH, 1, 0, 0);
    gemm_f32(he16, scP, kH, kIDense, kIDense, kH, 4, 1024, 1024);
    // h = dense_mlp0(h) -> t0P[0..3]
    dense_mlp(gu0_w, dn0_w);
    // h, r = add_rmsnorm(sum t0P[0..3], r, ln1)
    add_rmsnorm_kernel<<<kT, 256, 0, stream>>>(t0P, 4, r_buf, ln1_w, h32, h16, r_buf);
    // h = attention1(h) -> t0P[0..1]
    attention(qkv1_w, o1_w);
    // h, r = add_rmsnorm(sum t0P[0..1], r, pa1)
    add_rmsnorm_kernel<<<kT, 256, 0, stream>>>(t0P, 2, r_buf, pa1_w, h32, h16, r_buf);
    // h = dense_mlp1(h) -> t0P[0..3]
    dense_mlp(gu1_w, dn1_w);
    // out = (sum t0P + sum scP, r)
    final_out_kernel<<<(kT * kH / 4) / 256, 256, 0, stream>>>(t0P, scP, r_buf, out_h);
}

// Round 12
// 335.849 us; speedup vs baseline: 1.1561x; 1.0274x over previous
//
#include <hip/hip_runtime.h>
#include <math.h>

namespace {

constexpr int kT = 1024;
constexpr int kH = 1024;
constexpr int kNQ = 16;
constexpr int kNKV = 4;
constexpr int kD = 64;
constexpr int kQKV = (kNQ + 2 * kNKV) * kD;   // 1536
constexpr int kIDense = 4096;
constexpr int kIMoe = 512;
constexpr int kE = 8;
constexpr float kEps = 1e-6f;
constexpr long kTH = (long)kT * kH;

typedef __attribute__((ext_vector_type(8))) short short8;
typedef __attribute__((ext_vector_type(4))) float f32x4;

__device__ __forceinline__ ushort f2bf(float f) {
    union { float f; uint32_t u; } v; v.f = f;
    uint32_t r = (v.u + 0x7fffu + ((v.u >> 16) & 1u)) >> 16;
    return (ushort)r;
}
__device__ __forceinline__ void gload16(const void* g, void* l) {
    __builtin_amdgcn_global_load_lds(
        (const __attribute__((address_space(1))) void*)g,
        (__attribute__((address_space(3))) void*)l, 16, 0, 0);
}

// ---------------------------------------------------------------------------
// add + RMSNorm with fused nparts-sum
// ---------------------------------------------------------------------------
__global__ __launch_bounds__(256) void add_rmsnorm_kernel(
    const float* __restrict__ xP, int nparts, const float* __restrict__ res,
    const float* __restrict__ w, float* __restrict__ h32,
    ushort* __restrict__ h16, float* __restrict__ r_out)
{
    __shared__ float red[4];
    const int t = blockIdx.x;
    const int i = threadIdx.x;
    const size_t base = (size_t)t * kH;
    float4 s = reinterpret_cast<const float4*>(res + base)[i];
    for (int p = 0; p < nparts; p++) {
        float4 a = reinterpret_cast<const float4*>(xP + p * kTH + base)[i];
        s.x += a.x; s.y += a.y; s.z += a.z; s.w += a.w;
    }
    reinterpret_cast<float4*>(r_out + base)[i] = s;
    float ss = s.x * s.x + s.y * s.y + s.z * s.z + s.w * s.w;
    #pragma unroll
    for (int off = 32; off > 0; off >>= 1) ss += __shfl_down(ss, off);
    if ((i & 63) == 0) red[i >> 6] = ss;
    __syncthreads();
    const float tot = red[0] + red[1] + red[2] + red[3];
    const float inv = rsqrtf(tot * (1.0f / kH) + kEps);
    float4 wv = reinterpret_cast<const float4*>(w)[i];
    float4 o = make_float4(s.x * inv * wv.x, s.y * inv * wv.y,
                           s.z * inv * wv.z, s.w * inv * wv.w);
    reinterpret_cast<float4*>(h32 + base)[i] = o;
    ushort4 u;
    u.x = f2bf(o.x); u.y = f2bf(o.y); u.z = f2bf(o.z); u.w = f2bf(o.w);
    reinterpret_cast<ushort4*>(h16 + base)[i] = u;
}

// ---------------------------------------------------------------------------
// Fast transpose + f32 -> bf16
// ---------------------------------------------------------------------------
__global__ __launch_bounds__(256) void transpose_bf16_kernel(
    const float* __restrict__ W, ushort* __restrict__ WT,
    int R, int Cn, int ld_w, long w_z_stride, long wt_z_stride)
{
    __shared__ float tile[64 * 65];
    const int z = blockIdx.z;
    const float* Wz = W + (size_t)z * w_z_stride;
    ushort* WTz = WT + (size_t)z * wt_z_stride;
    const int r0 = blockIdx.y * 64;
    const int c0 = blockIdx.x * 64;
    const int tid = threadIdx.x;
    const int lr = tid >> 4;
    const int lc = (tid & 15) * 4;
    #pragma unroll
    for (int p = 0; p < 4; p++) {
        const int row = p * 16 + lr;
        float4 v = *reinterpret_cast<const float4*>(
            &Wz[(size_t)(r0 + row) * ld_w + c0 + lc]);
        tile[row * 65 + lc + 0] = v.x;
        tile[row * 65 + lc + 1] = v.y;
        tile[row * 65 + lc + 2] = v.z;
        tile[row * 65 + lc + 3] = v.w;
    }
    __syncthreads();
    const int ocl = tid >> 2;
    const int q = tid & 3;
    ushort u[16];
    #pragma unroll
    for (int e = 0; e < 16; e++)
        u[e] = f2bf(tile[(q * 16 + e) * 65 + ocl]);
    ushort* dst = &WTz[(size_t)(c0 + ocl) * R + r0 + q * 16];
    *reinterpret_cast<short8*>(dst) = *reinterpret_cast<short8*>(&u[0]);
    *reinterpret_cast<short8*>(dst + 8) = *reinterpret_cast<short8*>(&u[8]);
}

// ---------------------------------------------------------------------------
// bf16 MFMA GEMM, 64x64 tile, BK=64, 256 thr — r11 structure (skewed
// global_load_lds both sides, XCD swizzle, split-K plain-store parts)
// ---------------------------------------------------------------------------
template <bool GATED>
__global__ __launch_bounds__(256) void mgemm_kernel(
    const ushort* __restrict__ A, const ushort* __restrict__ B,
    float* __restrict__ Cf, ushort* __restrict__ C16,
    const float* __restrict__ scale,
    int lda, int ldb, int ldc, int kc,
    int gate_off_rows, long b_z_stride, int c_z_col, int k_z_off,
    int scale_stride, long c_fstride)
{
    __shared__ __align__(16) ushort As[64 * 64];
    __shared__ __align__(16) ushort Bs[64 * 64];
    __shared__ __align__(16) ushort Us[GATED ? 64 * 64 : 8];

    const int z = blockIdx.z;
    const int gy = gridDim.y;
    const int nf = gridDim.x * gy;
    const int fid = blockIdx.x + gridDim.x * blockIdx.y;
    const int qq = nf >> 3;
    const int id2 = (fid & 7) * qq + (fid >> 3);
    const int m0 = (id2 % gy) * 64;
    const int n0 = (id2 / gy) * 64;

    const int tid = threadIdx.x;
    const ushort* Bz = B + (size_t)z * b_z_stride;
    const int k0 = z * k_z_off;

    const int arow = tid >> 3;
    const int achk = tid & 7;

    const int lane = tid & 63;
    const int wave = tid >> 6;
    const int wr = (wave >> 1) * 32;
    const int wc = (wave & 1) * 32;
    const int lrow = lane & 15;
    const int lg = lane >> 4;

    f32x4 accg[2][2] = {};
    f32x4 accu[2][2] = {};

    for (int kk0 = 0; kk0 < kc; kk0 += 64) {
        const int kbase = k0 + kk0;
        #pragma unroll
        for (int c = 0; c < 2; c++) {
            const int row = c * 32 + arow;
            const int cs = (achk + (row & 7)) & 7;
            gload16(A + (size_t)(m0 + row) * lda + kbase + cs * 8,
                    (char*)As + c * 4096 + tid * 16);
            gload16(Bz + (size_t)(n0 + row) * ldb + kbase + cs * 8,
                    (char*)Bs + c * 4096 + tid * 16);
            if constexpr (GATED)
                gload16(Bz + (size_t)(gate_off_rows + n0 + row) * ldb + kbase + cs * 8,
                        (char*)Us + c * 4096 + tid * 16);
        }
        __syncthreads();

        short8 af[2][2], bfr[2][2];
        #pragma unroll
        for (int mf = 0; mf < 2; mf++)
            #pragma unroll
            for (int kk = 0; kk < 2; kk++) {
                const int r = wr + mf * 16 + lrow;
                const int sl = ((kk * 4 + lg) - (r & 7)) & 7;
                af[mf][kk] = *reinterpret_cast<const short8*>(
                    (const char*)As + r * 128 + sl * 16);
            }
        #pragma unroll
        for (int nf2 = 0; nf2 < 2; nf2++)
            #pragma unroll
            for (int kk = 0; kk < 2; kk++) {
                const int n = wc + nf2 * 16 + lrow;
                const int sl = ((kk * 4 + lg) - (n & 7)) & 7;
                bfr[nf2][kk] = *reinterpret_cast<const short8*>(
                    (const char*)Bs + n * 128 + sl * 16);
            }
        #pragma unroll
        for (int mf = 0; mf < 2; mf++)
            #pragma unroll
            for (int nf2 = 0; nf2 < 2; nf2++)
                #pragma unroll
                for (int kk = 0; kk < 2; kk++)
                    accg[mf][nf2] = __builtin_amdgcn_mfma_f32_16x16x32_bf16(
                        af[mf][kk], bfr[nf2][kk], accg[mf][nf2], 0, 0, 0);
        if constexpr (GATED) {
            short8 uf[2][2];
            #pragma unroll
            for (int nf2 = 0; nf2 < 2; nf2++)
                #pragma unroll
                for (int kk = 0; kk < 2; kk++) {
                    const int n = wc + nf2 * 16 + lrow;
                    const int sl = ((kk * 4 + lg) - (n & 7)) & 7;
                    uf[nf2][kk] = *reinterpret_cast<const short8*>(
                        (const char*)Us + n * 128 + sl * 16);
                }
            #pragma unroll
            for (int mf = 0; mf < 2; mf++)
                #pragma unroll
                for (int nf2 = 0; nf2 < 2; nf2++)
                    #pragma unroll
                    for (int kk = 0; kk < 2; kk++)
                        accu[mf][nf2] = __builtin_amdgcn_mfma_f32_16x16x32_bf16(
                            af[mf][kk], uf[nf2][kk], accu[mf][nf2], 0, 0, 0);
        }
        __syncthreads();
    }

    const int r4 = (lane >> 4) * 4;
    const int cl = lane & 15;
    const int ccol = z * c_z_col;
    float* Cfz = Cf ? Cf + (size_t)z * c_fstride : nullptr;
    #pragma unroll
    for (int mf = 0; mf < 2; mf++) {
        #pragma unroll
        for (int nf2 = 0; nf2 < 2; nf2++) {
            #pragma unroll
            for (int j = 0; j < 4; j++) {
                const int row = m0 + wr + mf * 16 + r4 + j;
                const int col = ccol + n0 + wc + nf2 * 16 + cl;
                if constexpr (GATED) {
                    const float g = accg[mf][nf2][j];
                    const float u = accu[mf][nf2][j];
                    const float sv =
                        scale ? scale[(size_t)row * scale_stride + z] : 1.0f;
                    const float h = (g / (1.0f + __expf(-g))) * u * sv;
                    C16[(size_t)row * ldc + col] = f2bf(h);
                } else {
                    Cfz[(size_t)row * ldc + col] = accg[mf][nf2][j];
                }
            }
        }
    }
}

// ---------------------------------------------------------------------------
// RoPE + bf16 pack
// ---------------------------------------------------------------------------
__global__ __launch_bounds__(256) void rope_pack_kernel(
    const float* __restrict__ qkv, const int* __restrict__ positions,
    ushort* __restrict__ Qb, ushort* __restrict__ Kb)
{
    const int t = blockIdx.x;
    const float pos = (float)positions[t];
    for (int item = threadIdx.x; item < (kNQ + kNKV) * 32; item += 256) {
        const int head = item >> 5;
        const int i = item & 31;
        const float inv_freq = powf(10000.0f, -(float)i * (1.0f / 32.0f));
        const float f = pos * inv_freq;
        float sv, cv;
        sincosf(f, &sv, &cv);
        const size_t off = (size_t)t * kQKV + head * kD;
        const float x1 = qkv[off + i];
        const float x2 = qkv[off + 32 + i];
        const float r1 = x1 * cv - x2 * sv;
        const float r2 = x2 * cv + x1 * sv;
        if (head < kNQ) {
            ushort* q = Qb + ((size_t)head * kT + t) * kD;
            q[i] = f2bf(r1 * 0.125f);
            q[i + 32] = f2bf(r2 * 0.125f);
        } else {
            ushort* k = Kb + ((size_t)(head - kNQ) * kT + t) * kD;
            k[i] = f2bf(r1);
            k[i + 32] = f2bf(r2);
        }
    }
}

// ---------------------------------------------------------------------------
// Router: logits = h32 @ gate_w, softmax, top-2 -> combine (T x 8)
// ---------------------------------------------------------------------------
__global__ __launch_bounds__(64) void gate_topk_kernel(
    const float* __restrict__ h, const float* __restrict__ gate_w,
    float* __restrict__ combine)
{
    const int t = blockIdx.x;
    const int lane = threadIdx.x;
    float acc[kE] = {};
    for (int i = lane; i < kH; i += 64) {
        const float xv = h[(size_t)t * kH + i];
        const float* gw = gate_w + (size_t)i * kE;
        #pragma unroll
        for (int e = 0; e < kE; e++) acc[e] += xv * gw[e];
    }
    #pragma unroll
    for (int e = 0; e < kE; e++) {
        #pragma unroll
        for (int off = 32; off > 0; off >>= 1) acc[e] += __shfl_down(acc[e], off);
    }
    if (lane == 0) {
        float mx = acc[0];
        #pragma unroll
        for (int e = 1; e < kE; e++) mx = fmaxf(mx, acc[e]);
        float p[kE];
        float s = 0.0f;
        #pragma unroll
        for (int e = 0; e < kE; e++) { p[e] = expf(acc[e] - mx); s += p[e]; }
        const float invs = 1.0f / s;
        #pragma unroll
        for (int e = 0; e < kE; e++) p[e] *= invs;
        int i1 = 0;
        #pragma unroll
        for (int e = 1; e < kE; e++) if (p[e] > p[i1]) i1 = e;
        int i2 = (i1 == 0) ? 1 : 0;
        #pragma unroll
        for (int e = 0; e < kE; e++) if (e != i1 && p[e] > p[i2]) i2 = e;
        float outv[kE];
        #pragma unroll
        for (int e = 0; e < kE; e++) outv[e] = 0.0f;
        outv[i1] = p[i1];
        outv[i2] = p[i2];
        #pragma unroll
        for (int e = 0; e < kE; e++) combine[(size_t)t * kE + e] = outv[e];
    }
}

// ---------------------------------------------------------------------------
// MFMA flash attention, KV-SPLIT (z=2 parts). Each part covers half the
// causal K-range for its q-tile and writes UNNORMALIZED O + (m,l) partials.
// Opart layout: [z][head][trow][64] f32; ml: [z][head][trow][2] f32.
// qtile index reversed so longest blocks dispatch first.
// ---------------------------------------------------------------------------
__global__ __launch_bounds__(256) void attn_mfma_kernel(
    const ushort* __restrict__ Qb, const ushort* __restrict__ Kb,
    const ushort* __restrict__ Vt, float* __restrict__ Opart,
    float* __restrict__ mlpart)
{
    __shared__ __align__(16) ushort Qs[64 * 64];
    __shared__ __align__(16) ushort Ks[64 * 64];
    __shared__ __align__(16) ushort Vs[64 * 64];
    __shared__ __align__(16) ushort Ps[64 * 64];
    const int tid = threadIdx.x;
    const int qbi = (int)gridDim.x - 1 - blockIdx.x;   // longest first
    const int qb = qbi * 64;
    const int hq = blockIdx.y;
    const int zp = blockIdx.z;
    const int kvh = hq >> 2;

    const int nt = qbi + 1;
    const int halfc = (nt + 1) >> 1;
    const int sbeg = zp ? halfc : 0;
    const int send = zp ? nt : halfc;

    float* Oz = Opart + (((size_t)zp * kNQ + hq) * kT + qb) * kD;
    float* mlz = mlpart + (((size_t)zp * kNQ + hq) * kT + qb) * 2;

    if (sbeg >= send) {          // empty part: exact-neutral partial
        for (int i = tid; i < 64 * kD; i += 256) Oz[(i >> 6) * kD + (i & 63)] = 0.f;
        for (int i = tid; i < 64; i += 256) { mlz[i * 2] = -1e30f; mlz[i * 2 + 1] = 0.f; }
        return;
    }

    const int lane = tid & 63;
    const int wave = tid >> 6;
    const int lrow = lane & 15;
    const int g = lane >> 4;
    const int srow = tid >> 3;
    const int sx = tid & 7;
    const ushort* Qg = Qb + ((size_t)hq * kT + qb) * kD;
    const ushort* Kg = Kb + (size_t)kvh * kT * kD;
    const ushort* Vg = Vt + (size_t)kvh * kD * kT;
    const int xr = (lrow & 7) << 4;

    #pragma unroll
    for (int c = 0; c < 2; c++) {
        const int row = c * 32 + srow;
        gload16(Qg + (size_t)row * kD + ((sx ^ (row & 7)) * 8),
                (char*)Qs + c * 4096 + tid * 16);
    }
    __syncthreads();
    short8 qf[2];
    #pragma unroll
    for (int kk = 0; kk < 2; kk++)
        qf[kk] = *reinterpret_cast<const short8*>(
            (const char*)Qs + (16 * wave + lrow) * 128 + ((kk * 64 + g * 16) ^ xr));

    f32x4 oacc[4] = {};
    float mrow = -1e30f, lsum = 0.0f;

    for (int ti = sbeg; ti < send; ++ti) {
        const int s0 = ti * 64;
        __syncthreads();
        #pragma unroll
        for (int c = 0; c < 2; c++) {
            const int row = c * 32 + srow;
            gload16(Kg + (size_t)(s0 + row) * kD + ((sx ^ (row & 7)) * 8),
                    (char*)Ks + c * 4096 + tid * 16);
            gload16(Vg + (size_t)row * kT + s0 + ((sx ^ (row & 7)) * 8),
                    (char*)Vs + c * 4096 + tid * 16);
        }
        __syncthreads();

        f32x4 sacc[4] = {};
        #pragma unroll
        for (int nf = 0; nf < 4; nf++) {
            #pragma unroll
            for (int kk = 0; kk < 2; kk++) {
                short8 kf = *reinterpret_cast<const short8*>(
                    (const char*)Ks + (nf * 16 + lrow) * 128 + ((kk * 64 + g * 16) ^ xr));
                sacc[nf] = __builtin_amdgcn_mfma_f32_16x16x32_bf16(
                    kf, qf[kk], sacc[nf], 0, 0, 0);
            }
        }

        const bool diag = (s0 == qb);
        float pv[16];
        float mloc = -1e30f;
        #pragma unroll
        for (int nf = 0; nf < 4; nf++)
            #pragma unroll
            for (int j = 0; j < 4; j++) {
                float s = sacc[nf][j];
                if (diag && (nf * 16 + g * 4 + j > 16 * wave + lrow)) s = -1e30f;
                pv[nf * 4 + j] = s;
                mloc = fmaxf(mloc, s);
            }
        mloc = fmaxf(mloc, __shfl_xor(mloc, 16));
        mloc = fmaxf(mloc, __shfl_xor(mloc, 32));
        const float mnew = fmaxf(mrow, mloc);
        const float alpha = __expf(mrow - mnew);
        float psum = 0.0f;
        #pragma unroll
        for (int j = 0; j < 16; j++) { pv[j] = __expf(pv[j] - mnew); psum += pv[j]; }
        psum += __shfl_xor(psum, 16);
        psum += __shfl_xor(psum, 32);
        lsum = lsum * alpha + psum;
        mrow = mnew;

        const int prow = 16 * wave + lrow;
        #pragma unroll
        for (int nf = 0; nf < 4; nf++)
            #pragma unroll
            for (int jp = 0; jp < 2; jp++) {
                uint32_t pk = (uint32_t)f2bf(pv[nf * 4 + jp * 2]) |
                              ((uint32_t)f2bf(pv[nf * 4 + jp * 2 + 1]) << 16);
                *reinterpret_cast<uint32_t*>(
                    (char*)Ps + prow * 128 + ((nf * 32 + g * 8 + jp * 4) ^ xr)) = pk;
            }

        float aj[4];
        #pragma unroll
        for (int j = 0; j < 4; j++) aj[j] = __shfl(alpha, g * 4 + j);
        #pragma unroll
        for (int nf = 0; nf < 4; nf++)
            #pragma unroll
            for (int j = 0; j < 4; j++) oacc[nf][j] *= aj[j];

        short8 paf[2];
        #pragma unroll
        for (int kk = 0; kk < 2; kk++)
            paf[kk] = *reinterpret_cast<const short8*>(
                (const char*)Ps + prow * 128 + ((kk * 64 + g * 16) ^ xr));
        #pragma unroll
        for (int nf = 0; nf < 4; nf++)
            #pragma unroll
            for (int kk = 0; kk < 2; kk++) {
                short8 vf = *reinterpret_cast<const short8*>(
                    (const char*)Vs + (nf * 16 + lrow) * 128 + ((kk * 64 + g * 16) ^ xr));
                oacc[nf] = __builtin_amdgcn_mfma_f32_16x16x32_bf16(
                    paf[kk], vf, oacc[nf], 0, 0, 0);
            }
    }

    // write unnormalized partial + (m,l)
    #pragma unroll
    for (int nf = 0; nf < 4; nf++)
        #pragma unroll
        for (int j = 0; j < 4; j++)
            Oz[(16 * wave + g * 4 + j) * kD + nf * 16 + lrow] = oacc[nf][j];
    if (g == 0) {
        mlz[(16 * wave + lrow) * 2 + 0] = mrow;
        mlz[(16 * wave + lrow) * 2 + 1] = lsum;
    }
}

// ---------------------------------------------------------------------------
// Merge 2 KV-split partials -> normalized bf16 attn output [T][16*64]
// block = token row; thread: head = tid>>4, cols (tid&15)*4
// ---------------------------------------------------------------------------
__global__ __launch_bounds__(256) void attn_merge_kernel(
    const float* __restrict__ Opart, const float* __restrict__ mlpart,
    ushort* __restrict__ attn_o)
{
    const int trow = blockIdx.x;
    const int tid = threadIdx.x;
    const int head = tid >> 4;
    const int c4 = (tid & 15) * 4;
    const size_t i0 = ((size_t)head * kT + trow);
    const size_t i1 = (((size_t)kNQ + head) * kT + trow);
    const float m0 = mlpart[i0 * 2], l0 = mlpart[i0 * 2 + 1];
    const float m1 = mlpart[i1 * 2], l1 = mlpart[i1 * 2 + 1];
    const float m = fmaxf(m0, m1);
    const float e0 = __expf(m0 - m), e1 = __expf(m1 - m);
    const float inv = 1.0f / (l0 * e0 + l1 * e1);
    float4 a = *reinterpret_cast<const float4*>(&Opart[i0 * kD + c4]);
    float4 b = *reinterpret_cast<const float4*>(&Opart[i1 * kD + c4]);
    ushort4 u;
    u.x = f2bf((a.x * e0 + b.x * e1) * inv);
    u.y = f2bf((a.y * e0 + b.y * e1) * inv);
    u.z = f2bf((a.z * e0 + b.z * e1) * inv);
    u.w = f2bf((a.w * e0 + b.w * e1) * inv);
    *reinterpret_cast<ushort4*>(
        &attn_o[(size_t)trow * (kNQ * kD) + head * kD + c4]) = u;
}

// ---------------------------------------------------------------------------
// final: out[0:TH] = sum(mlpP[0..3]) + sum(scP[0..3]); out[TH:] = r
// ---------------------------------------------------------------------------
__global__ __launch_bounds__(256) void final_out_kernel(
    const float* __restrict__ mlpP, const float* __restrict__ scP,
    const float* __restrict__ r, float* __restrict__ out)
{
    const int i = blockIdx.x * 256 + threadIdx.x;
    float4 s = make_float4(0.f, 0.f, 0.f, 0.f);
    #pragma unroll
    for (int p = 0; p < 4; p++) {
        float4 a = reinterpret_cast<const float4*>(mlpP + p * kTH)[i];
        float4 b = reinterpret_cast<const float4*>(scP + p * kTH)[i];
        s.x += a.x + b.x; s.y += a.y + b.y; s.z += a.z + b.z; s.w += a.w + b.w;
    }
    reinterpret_cast<float4*>(out)[i] = s;
    reinterpret_cast<float4*>(out + kTH)[i] =
        reinterpret_cast<const float4*>(r)[i];
}

}  // namespace

extern "C" void kernel_launch(void* const* d_in, const int* in_sizes, int n_in,
                              void* d_out, int out_size, void* d_ws, size_t ws_size,
                              hipStream_t stream) {
    (void)in_sizes; (void)n_in; (void)out_size; (void)ws_size;
    const float* hidden   = (const float*)d_in[0];
    const float* residual = (const float*)d_in[1];
    const int*   positions= (const int*)d_in[2];
    const float* ln0_w    = (const float*)d_in[3];
    const float* pa0_w    = (const float*)d_in[4];
    const float* ln1_w    = (const float*)d_in[5];
    const float* pa1_w    = (const float*)d_in[6];
    const float* qkv0_w   = (const float*)d_in[7];
    const float* o0_w     = (const float*)d_in[8];
    const float* qkv1_w   = (const float*)d_in[9];
    const float* o1_w     = (const float*)d_in[10];
    const float* gu0_w    = (const float*)d_in[11];
    const float* dn0_w    = (const float*)d_in[12];
    const float* gu1_w    = (const float*)d_in[13];
    const float* dn1_w    = (const float*)d_in[14];
    const float* gate_w   = (const float*)d_in[15];
    const float* w13      = (const float*)d_in[16];
    const float* w2       = (const float*)d_in[17];
    float* out_h = (float*)d_out;

    char* wsb = (char*)d_ws;
    float*  r_buf   = (float*)(wsb + (0ull  << 20));   // 4 MB
    float*  h32     = (float*)(wsb + (4ull  << 20));   // 4 MB
    float*  t0P     = (float*)(wsb + (8ull  << 20));   // 16 MB (4 split-K parts)
    float*  cb_buf  = (float*)(wsb + (8ull  << 20));   // 32 KB (time-disjoint w/ t0P)
    // Opart aliases t0P parts 2-3 (16..24 MB): free during both attentions
    float*  Opart   = (float*)(wsb + (16ull << 20));   // 8 MB
    float*  scP     = (float*)(wsb + (24ull << 20));   // 16 MB (4 parts)
    ushort* h16     = (ushort*)(wsb + (40ull << 20));  // 2 MB
    ushort* ao16    = (ushort*)(wsb + (42ull << 20));  // 2 MB
    float*  qkv_buf = (float*)(wsb + (44ull << 20));   // 6 MB (44..50, aliases he16)
    ushort* he16    = (ushort*)(wsb + (44ull << 20));  // 8 MB (44..52)
    float*  ml_buf  = (float*)(wsb + (50ull << 20));   // 256 KB (he16 tail, dead
                                                       //  during attention)
    ushort* wT      = (ushort*)(wsb + (52ull << 20));  // 16 MB (52..68)
    ushort* Qb      = (ushort*)(wsb + (62ull << 20));  // 2 MB (wT tail: only live
    ushort* Kb      = (ushort*)(wsb + (64ull << 20));  // 0.5 MB  while wT holds
    ushort* VtG     = (ushort*)(wsb + (65ull << 20));  // 0.5 MB  3MB qkv_w^T)

    auto transp = [&](const float* W, int R, int Cn, int nz, long zs_in, long zs_out) {
        transpose_bf16_kernel<<<dim3(Cn / 64, R / 64, nz), 256, 0, stream>>>(
            W, wT, R, Cn, Cn, zs_in, zs_out);
    };
    auto gemm_f32 = [&](const ushort* A, float* C, int N, int lda_,
                        int ldb_, int ldc_, int nz, int kc, int kzoff) {
        mgemm_kernel<false><<<dim3(N / 64, kT / 64, nz), 256, 0, stream>>>(
            A, wT, C, nullptr, nullptr, lda_, ldb_, ldc_, kc,
            0, 0, 0, kzoff, 0, kTH);
    };
    auto attention = [&](const float* qkv_w, const float* o_w) {
        transp(qkv_w, kH, kQKV, 1, 0, 0);
        mgemm_kernel<false><<<dim3(kQKV / 64, kT / 64, 1), 256, 0, stream>>>(
            h16, wT, qkv_buf, nullptr, nullptr, kH, kH, kQKV, kH,
            0, 0, 0, 0, 0, 0);
        rope_pack_kernel<<<kT, 256, 0, stream>>>(qkv_buf, positions, Qb, Kb);
        transpose_bf16_kernel<<<dim3(1, kT / 64, kNKV), 256, 0, stream>>>(
            qkv_buf + (kNQ + kNKV) * kD, VtG, kT, kD, kQKV, kD, (long)kD * kT);
        attn_mfma_kernel<<<dim3(kT / 64, kNQ, 2), 256, 0, stream>>>(
            Qb, Kb, VtG, Opart, ml_buf);
        attn_merge_kernel<<<kT, 256, 0, stream>>>(Opart, ml_buf, ao16);
        transp(o_w, kNQ * kD, kH, 1, 0, 0);
        gemm_f32(ao16, t0P, kH, kNQ * kD, kNQ * kD, kH, 2, 512, 512);
    };
    auto dense_mlp = [&](const float* gu_w, const float* dn_w) {
        transp(gu_w, kH, 2 * kIDense, 1, 0, 0);
        mgemm_kernel<true><<<dim3(kIDense / 64, kT / 64, 1), 256, 0, stream>>>(
            h16, wT, nullptr, he16, nullptr, kH, kH, kIDense, kH,
            kIDense, 0, 0, 0, 0, 0);
        transp(dn_w, kIDense, kH, 1, 0, 0);
        gemm_f32(he16, t0P, kH, kIDense, kIDense, kH, 4, 1024, 1024);
    };

    // h, r = add_rmsnorm(hidden, residual, ln0)
    add_rmsnorm_kernel<<<kT, 256, 0, stream>>>(hidden, 1, residual, ln0_w, h32, h16, r_buf);
    // h = attention0(h) -> t0P[0..1]
    attention(qkv0_w, o0_w);
    // h, r = add_rmsnorm(sum t0P[0..1], r, pa0)
    add_rmsnorm_kernel<<<kT, 256, 0, stream>>>(t0P, 2, r_buf, pa0_w, h32, h16, r_buf);
    // shortcut = moe(h) (dense, combine-scaled) -> scP[0..3]
    gate_topk_kernel<<<kT, 64, 0, stream>>>(h32, gate_w, cb_buf);
    transp(w13, kH, 2 * kIMoe, kE, (long)kH * 2 * kIMoe, (long)kH * 2 * kIMoe);
    mgemm_kernel<true><<<dim3(kIMoe / 64, kT / 64, kE), 256, 0, stream>>>(
        h16, wT, nullptr, he16, cb_buf, kH, kH, kIDense, kH,
        kIMoe, (long)kH * 2 * kIMoe, kIMoe, 0, kE, 0);
    transp(w2, kE * kIMoe, kH, 1, 0, 0);
    gemm_f32(he16, scP, kH, kIDense, kIDense, kH, 4, 1024, 1024);
    // h = dense_mlp0(h) -> t0P[0..3]
    dense_mlp(gu0_w, dn0_w);
    // h, r = add_rmsnorm(sum t0P[0..3], r, ln1)
    add_rmsnorm_kernel<<<kT, 256, 0, stream>>>(t0P, 4, r_buf, ln1_w, h32, h16, r_buf);
    // h = attention1(h) -> t0P[0..1]
    attention(qkv1_w, o1_w);
    // h, r = add_rmsnorm(sum t0P[0..1], r, pa1)
    add_rmsnorm_kernel<<<kT, 256, 0, stream>>>(t0P, 2, r_buf, pa1_w, h32, h16, r_buf);
    // h = dense_mlp1(h) -> t0P[0..3]
    dense_mlp(gu1_w, dn1_w);
    // out = (sum t0P + sum scP, r)
    final_out_kernel<<<(kT * kH / 4) / 256, 256, 0, stream>>>(t0P, scP, r_buf, out_h);
}

// Round 13
// 321.933 us; speedup vs baseline: 1.2061x; 1.0432x over previous
//
#include <hip/hip_runtime.h>
#include <math.h>

namespace {

constexpr int kT = 1024;
constexpr int kH = 1024;
constexpr int kNQ = 16;
constexpr int kNKV = 4;
constexpr int kD = 64;
constexpr int kQKV = (kNQ + 2 * kNKV) * kD;   // 1536
constexpr int kIDense = 4096;
constexpr int kIMoe = 512;
constexpr int kE = 8;
constexpr float kEps = 1e-6f;
constexpr long kTH = (long)kT * kH;

typedef __attribute__((ext_vector_type(8))) short short8;
typedef __attribute__((ext_vector_type(4))) float f32x4;

__device__ __forceinline__ ushort f2bf(float f) {
    union { float f; uint32_t u; } v; v.f = f;
    uint32_t r = (v.u + 0x7fffu + ((v.u >> 16) & 1u)) >> 16;
    return (ushort)r;
}
__device__ __forceinline__ void gload16(const void* g, void* l) {
    __builtin_amdgcn_global_load_lds(
        (const __attribute__((address_space(1))) void*)g,
        (__attribute__((address_space(3))) void*)l, 16, 0, 0);
}

// ---------------------------------------------------------------------------
// add + RMSNorm with fused nparts-sum
// ---------------------------------------------------------------------------
__global__ __launch_bounds__(256) void add_rmsnorm_kernel(
    const float* __restrict__ xP, int nparts, const float* __restrict__ res,
    const float* __restrict__ w, float* __restrict__ h32,
    ushort* __restrict__ h16, float* __restrict__ r_out)
{
    __shared__ float red[4];
    const int t = blockIdx.x;
    const int i = threadIdx.x;
    const size_t base = (size_t)t * kH;
    float4 s = reinterpret_cast<const float4*>(res + base)[i];
    for (int p = 0; p < nparts; p++) {
        float4 a = reinterpret_cast<const float4*>(xP + p * kTH + base)[i];
        s.x += a.x; s.y += a.y; s.z += a.z; s.w += a.w;
    }
    reinterpret_cast<float4*>(r_out + base)[i] = s;
    float ss = s.x * s.x + s.y * s.y + s.z * s.z + s.w * s.w;
    #pragma unroll
    for (int off = 32; off > 0; off >>= 1) ss += __shfl_down(ss, off);
    if ((i & 63) == 0) red[i >> 6] = ss;
    __syncthreads();
    const float tot = red[0] + red[1] + red[2] + red[3];
    const float inv = rsqrtf(tot * (1.0f / kH) + kEps);
    float4 wv = reinterpret_cast<const float4*>(w)[i];
    float4 o = make_float4(s.x * inv * wv.x, s.y * inv * wv.y,
                           s.z * inv * wv.z, s.w * inv * wv.w);
    reinterpret_cast<float4*>(h32 + base)[i] = o;
    ushort4 u;
    u.x = f2bf(o.x); u.y = f2bf(o.y); u.z = f2bf(o.z); u.w = f2bf(o.w);
    reinterpret_cast<ushort4*>(h16 + base)[i] = u;
}

// ---------------------------------------------------------------------------
// Fast transpose + f32 -> bf16
// ---------------------------------------------------------------------------
__global__ __launch_bounds__(256) void transpose_bf16_kernel(
    const float* __restrict__ W, ushort* __restrict__ WT,
    int R, int Cn, int ld_w, long w_z_stride, long wt_z_stride)
{
    __shared__ float tile[64 * 65];
    const int z = blockIdx.z;
    const float* Wz = W + (size_t)z * w_z_stride;
    ushort* WTz = WT + (size_t)z * wt_z_stride;
    const int r0 = blockIdx.y * 64;
    const int c0 = blockIdx.x * 64;
    const int tid = threadIdx.x;
    const int lr = tid >> 4;
    const int lc = (tid & 15) * 4;
    #pragma unroll
    for (int p = 0; p < 4; p++) {
        const int row = p * 16 + lr;
        float4 v = *reinterpret_cast<const float4*>(
            &Wz[(size_t)(r0 + row) * ld_w + c0 + lc]);
        tile[row * 65 + lc + 0] = v.x;
        tile[row * 65 + lc + 1] = v.y;
        tile[row * 65 + lc + 2] = v.z;
        tile[row * 65 + lc + 3] = v.w;
    }
    __syncthreads();
    const int ocl = tid >> 2;
    const int q = tid & 3;
    ushort u[16];
    #pragma unroll
    for (int e = 0; e < 16; e++)
        u[e] = f2bf(tile[(q * 16 + e) * 65 + ocl]);
    ushort* dst = &WTz[(size_t)(c0 + ocl) * R + r0 + q * 16];
    *reinterpret_cast<short8*>(dst) = *reinterpret_cast<short8*>(&u[0]);
    *reinterpret_cast<short8*>(dst + 8) = *reinterpret_cast<short8*>(&u[8]);
}

// ---------------------------------------------------------------------------
// bf16 MFMA GEMM, 64x64 tile, BK=64, 256 thr — r11 structure
// (used for qkv and o GEMMs)
// ---------------------------------------------------------------------------
template <bool GATED>
__global__ __launch_bounds__(256) void mgemm_kernel(
    const ushort* __restrict__ A, const ushort* __restrict__ B,
    float* __restrict__ Cf, ushort* __restrict__ C16,
    const float* __restrict__ scale,
    int lda, int ldb, int ldc, int kc,
    int gate_off_rows, long b_z_stride, int c_z_col, int k_z_off,
    int scale_stride, long c_fstride)
{
    __shared__ __align__(16) ushort As[64 * 64];
    __shared__ __align__(16) ushort Bs[64 * 64];
    __shared__ __align__(16) ushort Us[GATED ? 64 * 64 : 8];

    const int z = blockIdx.z;
    const int gy = gridDim.y;
    const int nf = gridDim.x * gy;
    const int fid = blockIdx.x + gridDim.x * blockIdx.y;
    const int qq = nf >> 3;
    const int id2 = (fid & 7) * qq + (fid >> 3);
    const int m0 = (id2 % gy) * 64;
    const int n0 = (id2 / gy) * 64;

    const int tid = threadIdx.x;
    const ushort* Bz = B + (size_t)z * b_z_stride;
    const int k0 = z * k_z_off;

    const int arow = tid >> 3;
    const int achk = tid & 7;

    const int lane = tid & 63;
    const int wave = tid >> 6;
    const int wr = (wave >> 1) * 32;
    const int wc = (wave & 1) * 32;
    const int lrow = lane & 15;
    const int lg = lane >> 4;

    f32x4 accg[2][2] = {};
    f32x4 accu[2][2] = {};

    for (int kk0 = 0; kk0 < kc; kk0 += 64) {
        const int kbase = k0 + kk0;
        #pragma unroll
        for (int c = 0; c < 2; c++) {
            const int row = c * 32 + arow;
            const int cs = (achk + (row & 7)) & 7;
            gload16(A + (size_t)(m0 + row) * lda + kbase + cs * 8,
                    (char*)As + c * 4096 + tid * 16);
            gload16(Bz + (size_t)(n0 + row) * ldb + kbase + cs * 8,
                    (char*)Bs + c * 4096 + tid * 16);
            if constexpr (GATED)
                gload16(Bz + (size_t)(gate_off_rows + n0 + row) * ldb + kbase + cs * 8,
                        (char*)Us + c * 4096 + tid * 16);
        }
        __syncthreads();

        short8 af[2][2], bfr[2][2];
        #pragma unroll
        for (int mf = 0; mf < 2; mf++)
            #pragma unroll
            for (int kk = 0; kk < 2; kk++) {
                const int r = wr + mf * 16 + lrow;
                const int sl = ((kk * 4 + lg) - (r & 7)) & 7;
                af[mf][kk] = *reinterpret_cast<const short8*>(
                    (const char*)As + r * 128 + sl * 16);
            }
        #pragma unroll
        for (int nf2 = 0; nf2 < 2; nf2++)
            #pragma unroll
            for (int kk = 0; kk < 2; kk++) {
                const int n = wc + nf2 * 16 + lrow;
                const int sl = ((kk * 4 + lg) - (n & 7)) & 7;
                bfr[nf2][kk] = *reinterpret_cast<const short8*>(
                    (const char*)Bs + n * 128 + sl * 16);
            }
        #pragma unroll
        for (int mf = 0; mf < 2; mf++)
            #pragma unroll
            for (int nf2 = 0; nf2 < 2; nf2++)
                #pragma unroll
                for (int kk = 0; kk < 2; kk++)
                    accg[mf][nf2] = __builtin_amdgcn_mfma_f32_16x16x32_bf16(
                        af[mf][kk], bfr[nf2][kk], accg[mf][nf2], 0, 0, 0);
        if constexpr (GATED) {
            short8 uf[2][2];
            #pragma unroll
            for (int nf2 = 0; nf2 < 2; nf2++)
                #pragma unroll
                for (int kk = 0; kk < 2; kk++) {
                    const int n = wc + nf2 * 16 + lrow;
                    const int sl = ((kk * 4 + lg) - (n & 7)) & 7;
                    uf[nf2][kk] = *reinterpret_cast<const short8*>(
                        (const char*)Us + n * 128 + sl * 16);
                }
            #pragma unroll
            for (int mf = 0; mf < 2; mf++)
                #pragma unroll
                for (int nf2 = 0; nf2 < 2; nf2++)
                    #pragma unroll
                    for (int kk = 0; kk < 2; kk++)
                        accu[mf][nf2] = __builtin_amdgcn_mfma_f32_16x16x32_bf16(
                            af[mf][kk], uf[nf2][kk], accu[mf][nf2], 0, 0, 0);
        }
        __syncthreads();
    }

    const int r4 = (lane >> 4) * 4;
    const int cl = lane & 15;
    const int ccol = z * c_z_col;
    float* Cfz = Cf ? Cf + (size_t)z * c_fstride : nullptr;
    #pragma unroll
    for (int mf = 0; mf < 2; mf++) {
        #pragma unroll
        for (int nf2 = 0; nf2 < 2; nf2++) {
            #pragma unroll
            for (int j = 0; j < 4; j++) {
                const int row = m0 + wr + mf * 16 + r4 + j;
                const int col = ccol + n0 + wc + nf2 * 16 + cl;
                if constexpr (GATED) {
                    const float g = accg[mf][nf2][j];
                    const float u = accu[mf][nf2][j];
                    const float sv =
                        scale ? scale[(size_t)row * scale_stride + z] : 1.0f;
                    const float h = (g / (1.0f + __expf(-g))) * u * sv;
                    C16[(size_t)row * ldc + col] = f2bf(h);
                } else {
                    Cfz[(size_t)row * ldc + col] = accg[mf][nf2][j];
                }
            }
        }
    }
}

// ---------------------------------------------------------------------------
// bf16 MFMA GEMM, 64x128 tile, BK=64, 512 thr (8 waves 2m x 4n, 2x2 frags).
// Same staging/skew/frag patterns as mgemm_kernel; doubled N per block for
// 2x A-reuse and halved B-traffic/FLOP. Used for gu/w13/dn/w2.
// ---------------------------------------------------------------------------
template <bool GATED>
__global__ __launch_bounds__(512) void mgemm128_kernel(
    const ushort* __restrict__ A, const ushort* __restrict__ B,
    float* __restrict__ Cf, ushort* __restrict__ C16,
    const float* __restrict__ scale,
    int lda, int ldb, int ldc, int kc,
    int gate_off_rows, long b_z_stride, int c_z_col, int k_z_off,
    int scale_stride, long c_fstride)
{
    __shared__ __align__(16) ushort As[64 * 64];
    __shared__ __align__(16) ushort Bs[128 * 64];
    __shared__ __align__(16) ushort Us[GATED ? 128 * 64 : 8];

    const int z = blockIdx.z;
    const int gy = gridDim.y;
    const int nf = gridDim.x * gy;
    const int fid = blockIdx.x + gridDim.x * blockIdx.y;
    const int qq = nf >> 3;
    const int id2 = (fid & 7) * qq + (fid >> 3);
    const int m0 = (id2 % gy) * 64;
    const int n0 = (id2 / gy) * 128;

    const int tid = threadIdx.x;
    const ushort* Bz = B + (size_t)z * b_z_stride;
    const int k0 = z * k_z_off;

    const int sr = tid >> 3;             // 0..63
    const int sc = tid & 7;

    const int lane = tid & 63;
    const int wave = tid >> 6;
    const int wr = (wave >> 2) * 32;     // 2 m-rows of 32
    const int wc = (wave & 3) * 32;      // 4 n-cols of 32
    const int lrow = lane & 15;
    const int lg = lane >> 4;

    f32x4 accg[2][2] = {};
    f32x4 accu[2][2] = {};

    for (int kk0 = 0; kk0 < kc; kk0 += 64) {
        const int kbase = k0 + kk0;
        {   // A: 64 rows in one shot (512 thr x 16B = 8KB)
            const int csA = (sc + (sr & 7)) & 7;
            gload16(A + (size_t)(m0 + sr) * lda + kbase + csA * 8,
                    (char*)As + tid * 16);
        }
        #pragma unroll
        for (int c = 0; c < 2; c++) {    // B/U: 128 rows in 2 chunks
            const int row = c * 64 + sr;
            const int cs = (sc + (row & 7)) & 7;
            gload16(Bz + (size_t)(n0 + row) * ldb + kbase + cs * 8,
                    (char*)Bs + c * 8192 + tid * 16);
            if constexpr (GATED)
                gload16(Bz + (size_t)(gate_off_rows + n0 + row) * ldb + kbase + cs * 8,
                        (char*)Us + c * 8192 + tid * 16);
        }
        __syncthreads();

        short8 af[2][2], bfr[2][2];
        #pragma unroll
        for (int mf = 0; mf < 2; mf++)
            #pragma unroll
            for (int kk = 0; kk < 2; kk++) {
                const int r = wr + mf * 16 + lrow;
                const int sl = ((kk * 4 + lg) - (r & 7)) & 7;
                af[mf][kk] = *reinterpret_cast<const short8*>(
                    (const char*)As + r * 128 + sl * 16);
            }
        #pragma unroll
        for (int nf2 = 0; nf2 < 2; nf2++)
            #pragma unroll
            for (int kk = 0; kk < 2; kk++) {
                const int n = wc + nf2 * 16 + lrow;
                const int sl = ((kk * 4 + lg) - (n & 7)) & 7;
                bfr[nf2][kk] = *reinterpret_cast<const short8*>(
                    (const char*)Bs + n * 128 + sl * 16);
            }
        #pragma unroll
        for (int mf = 0; mf < 2; mf++)
            #pragma unroll
            for (int nf2 = 0; nf2 < 2; nf2++)
                #pragma unroll
                for (int kk = 0; kk < 2; kk++)
                    accg[mf][nf2] = __builtin_amdgcn_mfma_f32_16x16x32_bf16(
                        af[mf][kk], bfr[nf2][kk], accg[mf][nf2], 0, 0, 0);
        if constexpr (GATED) {
            short8 uf[2][2];
            #pragma unroll
            for (int nf2 = 0; nf2 < 2; nf2++)
                #pragma unroll
                for (int kk = 0; kk < 2; kk++) {
                    const int n = wc + nf2 * 16 + lrow;
                    const int sl = ((kk * 4 + lg) - (n & 7)) & 7;
                    uf[nf2][kk] = *reinterpret_cast<const short8*>(
                        (const char*)Us + n * 128 + sl * 16);
                }
            #pragma unroll
            for (int mf = 0; mf < 2; mf++)
                #pragma unroll
                for (int nf2 = 0; nf2 < 2; nf2++)
                    #pragma unroll
                    for (int kk = 0; kk < 2; kk++)
                        accu[mf][nf2] = __builtin_amdgcn_mfma_f32_16x16x32_bf16(
                            af[mf][kk], uf[nf2][kk], accu[mf][nf2], 0, 0, 0);
        }
        __syncthreads();
    }

    const int r4 = (lane >> 4) * 4;
    const int cl = lane & 15;
    const int ccol = z * c_z_col;
    float* Cfz = Cf ? Cf + (size_t)z * c_fstride : nullptr;
    #pragma unroll
    for (int mf = 0; mf < 2; mf++) {
        #pragma unroll
        for (int nf2 = 0; nf2 < 2; nf2++) {
            #pragma unroll
            for (int j = 0; j < 4; j++) {
                const int row = m0 + wr + mf * 16 + r4 + j;
                const int col = ccol + n0 + wc + nf2 * 16 + cl;
                if constexpr (GATED) {
                    const float g = accg[mf][nf2][j];
                    const float u = accu[mf][nf2][j];
                    const float sv =
                        scale ? scale[(size_t)row * scale_stride + z] : 1.0f;
                    const float h = (g / (1.0f + __expf(-g))) * u * sv;
                    C16[(size_t)row * ldc + col] = f2bf(h);
                } else {
                    Cfz[(size_t)row * ldc + col] = accg[mf][nf2][j];
                }
            }
        }
    }
}

// ---------------------------------------------------------------------------
// RoPE + bf16 pack
// ---------------------------------------------------------------------------
__global__ __launch_bounds__(256) void rope_pack_kernel(
    const float* __restrict__ qkv, const int* __restrict__ positions,
    ushort* __restrict__ Qb, ushort* __restrict__ Kb)
{
    const int t = blockIdx.x;
    const float pos = (float)positions[t];
    for (int item = threadIdx.x; item < (kNQ + kNKV) * 32; item += 256) {
        const int head = item >> 5;
        const int i = item & 31;
        const float inv_freq = powf(10000.0f, -(float)i * (1.0f / 32.0f));
        const float f = pos * inv_freq;
        float sv, cv;
        sincosf(f, &sv, &cv);
        const size_t off = (size_t)t * kQKV + head * kD;
        const float x1 = qkv[off + i];
        const float x2 = qkv[off + 32 + i];
        const float r1 = x1 * cv - x2 * sv;
        const float r2 = x2 * cv + x1 * sv;
        if (head < kNQ) {
            ushort* q = Qb + ((size_t)head * kT + t) * kD;
            q[i] = f2bf(r1 * 0.125f);
            q[i + 32] = f2bf(r2 * 0.125f);
        } else {
            ushort* k = Kb + ((size_t)(head - kNQ) * kT + t) * kD;
            k[i] = f2bf(r1);
            k[i + 32] = f2bf(r2);
        }
    }
}

// ---------------------------------------------------------------------------
// Router: logits = h32 @ gate_w, softmax, top-2 -> combine (T x 8)
// ---------------------------------------------------------------------------
__global__ __launch_bounds__(64) void gate_topk_kernel(
    const float* __restrict__ h, const float* __restrict__ gate_w,
    float* __restrict__ combine)
{
    const int t = blockIdx.x;
    const int lane = threadIdx.x;
    float acc[kE] = {};
    for (int i = lane; i < kH; i += 64) {
        const float xv = h[(size_t)t * kH + i];
        const float* gw = gate_w + (size_t)i * kE;
        #pragma unroll
        for (int e = 0; e < kE; e++) acc[e] += xv * gw[e];
    }
    #pragma unroll
    for (int e = 0; e < kE; e++) {
        #pragma unroll
        for (int off = 32; off > 0; off >>= 1) acc[e] += __shfl_down(acc[e], off);
    }
    if (lane == 0) {
        float mx = acc[0];
        #pragma unroll
        for (int e = 1; e < kE; e++) mx = fmaxf(mx, acc[e]);
        float p[kE];
        float s = 0.0f;
        #pragma unroll
        for (int e = 0; e < kE; e++) { p[e] = expf(acc[e] - mx); s += p[e]; }
        const float invs = 1.0f / s;
        #pragma unroll
        for (int e = 0; e < kE; e++) p[e] *= invs;
        int i1 = 0;
        #pragma unroll
        for (int e = 1; e < kE; e++) if (p[e] > p[i1]) i1 = e;
        int i2 = (i1 == 0) ? 1 : 0;
        #pragma unroll
        for (int e = 0; e < kE; e++) if (e != i1 && p[e] > p[i2]) i2 = e;
        float outv[kE];
        #pragma unroll
        for (int e = 0; e < kE; e++) outv[e] = 0.0f;
        outv[i1] = p[i1];
        outv[i2] = p[i2];
        #pragma unroll
        for (int e = 0; e < kE; e++) combine[(size_t)t * kE + e] = outv[e];
    }
}

// ---------------------------------------------------------------------------
// MFMA flash attention, KV-SPLIT (z=2) — r12 structure
// ---------------------------------------------------------------------------
__global__ __launch_bounds__(256) void attn_mfma_kernel(
    const ushort* __restrict__ Qb, const ushort* __restrict__ Kb,
    const ushort* __restrict__ Vt, float* __restrict__ Opart,
    float* __restrict__ mlpart)
{
    __shared__ __align__(16) ushort Qs[64 * 64];
    __shared__ __align__(16) ushort Ks[64 * 64];
    __shared__ __align__(16) ushort Vs[64 * 64];
    __shared__ __align__(16) ushort Ps[64 * 64];
    const int tid = threadIdx.x;
    const int qbi = (int)gridDim.x - 1 - blockIdx.x;
    const int qb = qbi * 64;
    const int hq = blockIdx.y;
    const int zp = blockIdx.z;
    const int kvh = hq >> 2;

    const int nt = qbi + 1;
    const int halfc = (nt + 1) >> 1;
    const int sbeg = zp ? halfc : 0;
    const int send = zp ? nt : halfc;

    float* Oz = Opart + (((size_t)zp * kNQ + hq) * kT + qb) * kD;
    float* mlz = mlpart + (((size_t)zp * kNQ + hq) * kT + qb) * 2;

    if (sbeg >= send) {
        for (int i = tid; i < 64 * kD; i += 256) Oz[(i >> 6) * kD + (i & 63)] = 0.f;
        for (int i = tid; i < 64; i += 256) { mlz[i * 2] = -1e30f; mlz[i * 2 + 1] = 0.f; }
        return;
    }

    const int lane = tid & 63;
    const int wave = tid >> 6;
    const int lrow = lane & 15;
    const int g = lane >> 4;
    const int srow = tid >> 3;
    const int sx = tid & 7;
    const ushort* Qg = Qb + ((size_t)hq * kT + qb) * kD;
    const ushort* Kg = Kb + (size_t)kvh * kT * kD;
    const ushort* Vg = Vt + (size_t)kvh * kD * kT;
    const int xr = (lrow & 7) << 4;

    #pragma unroll
    for (int c = 0; c < 2; c++) {
        const int row = c * 32 + srow;
        gload16(Qg + (size_t)row * kD + ((sx ^ (row & 7)) * 8),
                (char*)Qs + c * 4096 + tid * 16);
    }
    __syncthreads();
    short8 qf[2];
    #pragma unroll
    for (int kk = 0; kk < 2; kk++)
        qf[kk] = *reinterpret_cast<const short8*>(
            (const char*)Qs + (16 * wave + lrow) * 128 + ((kk * 64 + g * 16) ^ xr));

    f32x4 oacc[4] = {};
    float mrow = -1e30f, lsum = 0.0f;

    for (int ti = sbeg; ti < send; ++ti) {
        const int s0 = ti * 64;
        __syncthreads();
        #pragma unroll
        for (int c = 0; c < 2; c++) {
            const int row = c * 32 + srow;
            gload16(Kg + (size_t)(s0 + row) * kD + ((sx ^ (row & 7)) * 8),
                    (char*)Ks + c * 4096 + tid * 16);
            gload16(Vg + (size_t)row * kT + s0 + ((sx ^ (row & 7)) * 8),
                    (char*)Vs + c * 4096 + tid * 16);
        }
        __syncthreads();

        f32x4 sacc[4] = {};
        #pragma unroll
        for (int nf = 0; nf < 4; nf++) {
            #pragma unroll
            for (int kk = 0; kk < 2; kk++) {
                short8 kf = *reinterpret_cast<const short8*>(
                    (const char*)Ks + (nf * 16 + lrow) * 128 + ((kk * 64 + g * 16) ^ xr));
                sacc[nf] = __builtin_amdgcn_mfma_f32_16x16x32_bf16(
                    kf, qf[kk], sacc[nf], 0, 0, 0);
            }
        }

        const bool diag = (s0 == qb);
        float pv[16];
        float mloc = -1e30f;
        #pragma unroll
        for (int nf = 0; nf < 4; nf++)
            #pragma unroll
            for (int j = 0; j < 4; j++) {
                float s = sacc[nf][j];
                if (diag && (nf * 16 + g * 4 + j > 16 * wave + lrow)) s = -1e30f;
                pv[nf * 4 + j] = s;
                mloc = fmaxf(mloc, s);
            }
        mloc = fmaxf(mloc, __shfl_xor(mloc, 16));
        mloc = fmaxf(mloc, __shfl_xor(mloc, 32));
        const float mnew = fmaxf(mrow, mloc);
        const float alpha = __expf(mrow - mnew);
        float psum = 0.0f;
        #pragma unroll
        for (int j = 0; j < 16; j++) { pv[j] = __expf(pv[j] - mnew); psum += pv[j]; }
        psum += __shfl_xor(psum, 16);
        psum += __shfl_xor(psum, 32);
        lsum = lsum * alpha + psum;
        mrow = mnew;

        const int prow = 16 * wave + lrow;
        #pragma unroll
        for (int nf = 0; nf < 4; nf++)
            #pragma unroll
            for (int jp = 0; jp < 2; jp++) {
                uint32_t pk = (uint32_t)f2bf(pv[nf * 4 + jp * 2]) |
                              ((uint32_t)f2bf(pv[nf * 4 + jp * 2 + 1]) << 16);
                *reinterpret_cast<uint32_t*>(
                    (char*)Ps + prow * 128 + ((nf * 32 + g * 8 + jp * 4) ^ xr)) = pk;
            }

        float aj[4];
        #pragma unroll
        for (int j = 0; j < 4; j++) aj[j] = __shfl(alpha, g * 4 + j);
        #pragma unroll
        for (int nf = 0; nf < 4; nf++)
            #pragma unroll
            for (int j = 0; j < 4; j++) oacc[nf][j] *= aj[j];

        short8 paf[2];
        #pragma unroll
        for (int kk = 0; kk < 2; kk++)
            paf[kk] = *reinterpret_cast<const short8*>(
                (const char*)Ps + prow * 128 + ((kk * 64 + g * 16) ^ xr));
        #pragma unroll
        for (int nf = 0; nf < 4; nf++)
            #pragma unroll
            for (int kk = 0; kk < 2; kk++) {
                short8 vf = *reinterpret_cast<const short8*>(
                    (const char*)Vs + (nf * 16 + lrow) * 128 + ((kk * 64 + g * 16) ^ xr));
                oacc[nf] = __builtin_amdgcn_mfma_f32_16x16x32_bf16(
                    paf[kk], vf, oacc[nf], 0, 0, 0);
            }
    }

    #pragma unroll
    for (int nf = 0; nf < 4; nf++)
        #pragma unroll
        for (int j = 0; j < 4; j++)
            Oz[(16 * wave + g * 4 + j) * kD + nf * 16 + lrow] = oacc[nf][j];
    if (g == 0) {
        mlz[(16 * wave + lrow) * 2 + 0] = mrow;
        mlz[(16 * wave + lrow) * 2 + 1] = lsum;
    }
}

// ---------------------------------------------------------------------------
// Merge 2 KV-split partials -> normalized bf16 attn output
// ---------------------------------------------------------------------------
__global__ __launch_bounds__(256) void attn_merge_kernel(
    const float* __restrict__ Opart, const float* __restrict__ mlpart,
    ushort* __restrict__ attn_o)
{
    const int trow = blockIdx.x;
    const int tid = threadIdx.x;
    const int head = tid >> 4;
    const int c4 = (tid & 15) * 4;
    const size_t i0 = ((size_t)head * kT + trow);
    const size_t i1 = (((size_t)kNQ + head) * kT + trow);
    const float m0 = mlpart[i0 * 2], l0 = mlpart[i0 * 2 + 1];
    const float m1 = mlpart[i1 * 2], l1 = mlpart[i1 * 2 + 1];
    const float m = fmaxf(m0, m1);
    const float e0 = __expf(m0 - m), e1 = __expf(m1 - m);
    const float inv = 1.0f / (l0 * e0 + l1 * e1);
    float4 a = *reinterpret_cast<const float4*>(&Opart[i0 * kD + c4]);
    float4 b = *reinterpret_cast<const float4*>(&Opart[i1 * kD + c4]);
    ushort4 u;
    u.x = f2bf((a.x * e0 + b.x * e1) * inv);
    u.y = f2bf((a.y * e0 + b.y * e1) * inv);
    u.z = f2bf((a.z * e0 + b.z * e1) * inv);
    u.w = f2bf((a.w * e0 + b.w * e1) * inv);
    *reinterpret_cast<ushort4*>(
        &attn_o[(size_t)trow * (kNQ * kD) + head * kD + c4]) = u;
}

// ---------------------------------------------------------------------------
// final: out[0:TH] = sum(mlpP[0..3]) + sum(scP[0..3]); out[TH:] = r
// ---------------------------------------------------------------------------
__global__ __launch_bounds__(256) void final_out_kernel(
    const float* __restrict__ mlpP, const float* __restrict__ scP,
    const float* __restrict__ r, float* __restrict__ out)
{
    const int i = blockIdx.x * 256 + threadIdx.x;
    float4 s = make_float4(0.f, 0.f, 0.f, 0.f);
    #pragma unroll
    for (int p = 0; p < 4; p++) {
        float4 a = reinterpret_cast<const float4*>(mlpP + p * kTH)[i];
        float4 b = reinterpret_cast<const float4*>(scP + p * kTH)[i];
        s.x += a.x + b.x; s.y += a.y + b.y; s.z += a.z + b.z; s.w += a.w + b.w;
    }
    reinterpret_cast<float4*>(out)[i] = s;
    reinterpret_cast<float4*>(out + kTH)[i] =
        reinterpret_cast<const float4*>(r)[i];
}

}  // namespace

extern "C" void kernel_launch(void* const* d_in, const int* in_sizes, int n_in,
                              void* d_out, int out_size, void* d_ws, size_t ws_size,
                              hipStream_t stream) {
    (void)in_sizes; (void)n_in; (void)out_size; (void)ws_size;
    const float* hidden   = (const float*)d_in[0];
    const float* residual = (const float*)d_in[1];
    const int*   positions= (const int*)d_in[2];
    const float* ln0_w    = (const float*)d_in[3];
    const float* pa0_w    = (const float*)d_in[4];
    const float* ln1_w    = (const float*)d_in[5];
    const float* pa1_w    = (const float*)d_in[6];
    const float* qkv0_w   = (const float*)d_in[7];
    const float* o0_w     = (const float*)d_in[8];
    const float* qkv1_w   = (const float*)d_in[9];
    const float* o1_w     = (const float*)d_in[10];
    const float* gu0_w    = (const float*)d_in[11];
    const float* dn0_w    = (const float*)d_in[12];
    const float* gu1_w    = (const float*)d_in[13];
    const float* dn1_w    = (const float*)d_in[14];
    const float* gate_w   = (const float*)d_in[15];
    const float* w13      = (const float*)d_in[16];
    const float* w2       = (const float*)d_in[17];
    float* out_h = (float*)d_out;

    char* wsb = (char*)d_ws;
    float*  r_buf   = (float*)(wsb + (0ull  << 20));   // 4 MB
    float*  h32     = (float*)(wsb + (4ull  << 20));   // 4 MB
    float*  t0P     = (float*)(wsb + (8ull  << 20));   // 16 MB (4 split-K parts)
    float*  cb_buf  = (float*)(wsb + (8ull  << 20));   // 32 KB (time-disjoint w/ t0P)
    float*  Opart   = (float*)(wsb + (16ull << 20));   // 8 MB (t0P parts 2-3)
    float*  scP     = (float*)(wsb + (24ull << 20));   // 16 MB (4 parts)
    ushort* h16     = (ushort*)(wsb + (40ull << 20));  // 2 MB
    ushort* ao16    = (ushort*)(wsb + (42ull << 20));  // 2 MB
    float*  qkv_buf = (float*)(wsb + (44ull << 20));   // 6 MB (aliases he16)
    ushort* he16    = (ushort*)(wsb + (44ull << 20));  // 8 MB (44..52)
    float*  ml_buf  = (float*)(wsb + (50ull << 20));   // 256 KB (he16 tail)
    ushort* wT      = (ushort*)(wsb + (52ull << 20));  // 16 MB (52..68)
    ushort* Qb      = (ushort*)(wsb + (62ull << 20));  // 2 MB (wT tail, dead zone)
    ushort* Kb      = (ushort*)(wsb + (64ull << 20));  // 0.5 MB
    ushort* VtG     = (ushort*)(wsb + (65ull << 20));  // 0.5 MB

    auto transp = [&](const float* W, int R, int Cn, int nz, long zs_in, long zs_out) {
        transpose_bf16_kernel<<<dim3(Cn / 64, R / 64, nz), 256, 0, stream>>>(
            W, wT, R, Cn, Cn, zs_in, zs_out);
    };
    auto attention = [&](const float* qkv_w, const float* o_w) {
        transp(qkv_w, kH, kQKV, 1, 0, 0);
        mgemm_kernel<false><<<dim3(kQKV / 64, kT / 64, 1), 256, 0, stream>>>(
            h16, wT, qkv_buf, nullptr, nullptr, kH, kH, kQKV, kH,
            0, 0, 0, 0, 0, 0);
        rope_pack_kernel<<<kT, 256, 0, stream>>>(qkv_buf, positions, Qb, Kb);
        transpose_bf16_kernel<<<dim3(1, kT / 64, kNKV), 256, 0, stream>>>(
            qkv_buf + (kNQ + kNKV) * kD, VtG, kT, kD, kQKV, kD, (long)kD * kT);
        attn_mfma_kernel<<<dim3(kT / 64, kNQ, 2), 256, 0, stream>>>(
            Qb, Kb, VtG, Opart, ml_buf);
        attn_merge_kernel<<<kT, 256, 0, stream>>>(Opart, ml_buf, ao16);
        transp(o_w, kNQ * kD, kH, 1, 0, 0);
        mgemm_kernel<false><<<dim3(kH / 64, kT / 64, 2), 256, 0, stream>>>(
            ao16, wT, t0P, nullptr, nullptr, kNQ * kD, kNQ * kD, kH, 512,
            0, 0, 0, 512, 0, kTH);
    };
    auto dense_mlp = [&](const float* gu_w, const float* dn_w) {
        transp(gu_w, kH, 2 * kIDense, 1, 0, 0);
        mgemm128_kernel<true><<<dim3(kIDense / 128, kT / 64, 1), 512, 0, stream>>>(
            h16, wT, nullptr, he16, nullptr, kH, kH, kIDense, kH,
            kIDense, 0, 0, 0, 0, 0);
        transp(dn_w, kIDense, kH, 1, 0, 0);
        mgemm128_kernel<false><<<dim3(kH / 128, kT / 64, 4), 512, 0, stream>>>(
            he16, wT, t0P, nullptr, nullptr, kIDense, kIDense, kH, 1024,
            0, 0, 0, 1024, 0, kTH);
    };

    // h, r = add_rmsnorm(hidden, residual, ln0)
    add_rmsnorm_kernel<<<kT, 256, 0, stream>>>(hidden, 1, residual, ln0_w, h32, h16, r_buf);
    // h = attention0(h) -> t0P[0..1]
    attention(qkv0_w, o0_w);
    // h, r = add_rmsnorm(sum t0P[0..1], r, pa0)
    add_rmsnorm_kernel<<<kT, 256, 0, stream>>>(t0P, 2, r_buf, pa0_w, h32, h16, r_buf);
    // shortcut = moe(h) (dense, combine-scaled) -> scP[0..3]
    gate_topk_kernel<<<kT, 64, 0, stream>>>(h32, gate_w, cb_buf);
    transp(w13, kH, 2 * kIMoe, kE, (long)kH * 2 * kIMoe, (long)kH * 2 * kIMoe);
    mgemm128_kernel<true><<<dim3(kIMoe / 128, kT / 64, kE), 512, 0, stream>>>(
        h16, wT, nullptr, he16, cb_buf, kH, kH, kIDense, kH,
        kIMoe, (long)kH * 2 * kIMoe, kIMoe, 0, kE, 0);
    transp(w2, kE * kIMoe, kH, 1, 0, 0);
    mgemm128_kernel<false><<<dim3(kH / 128, kT / 64, 4), 512, 0, stream>>>(
        he16, wT, scP, nullptr, nullptr, kIDense, kIDense, kH, 1024,
        0, 0, 0, 1024, 0, kTH);
    // h = dense_mlp0(h) -> t0P[0..3]
    dense_mlp(gu0_w, dn0_w);
    // h, r = add_rmsnorm(sum t0P[0..3], r, ln1)
    add_rmsnorm_kernel<<<kT, 256, 0, stream>>>(t0P, 4, r_buf, ln1_w, h32, h16, r_buf);
    // h = attention1(h) -> t0P[0..1]
    attention(qkv1_w, o1_w);
    // h, r = add_rmsnorm(sum t0P[0..1], r, pa1)
    add_rmsnorm_kernel<<<kT, 256, 0, stream>>>(t0P, 2, r_buf, pa1_w, h32, h16, r_buf);
    // h = dense_mlp1(h) -> t0P[0..3]
    dense_mlp(gu1_w, dn1_w);
    // out = (sum t0P + sum scP, r)
    final_out_kernel<<<(kT * kH / 4) / 256, 256, 0, stream>>>(t0P, scP, r_buf, out_h);
}